// Round 5
// baseline (2106.686 us; speedup 1.0000x reference)
//
#include <hip/hip_runtime.h>

#define NCH   256
#define M_PIX 262144
#define MPAD  266240   // 520*512 ; >= M_PIX + 8*512 worst-case alignment pad
#define LDA   40       // padded LDS leading dim (bf16 elements) for 32-wide k tiles

typedef short bf16x8 __attribute__((ext_vector_type(8)));
typedef float f32x4  __attribute__((ext_vector_type(4)));

__device__ __forceinline__ unsigned short f2bf(float f) {
  union { float f; unsigned u; } v; v.f = f;
  unsigned r = v.u + 0x7FFFu + ((v.u >> 16) & 1u);
  return (unsigned short)(r >> 16);
}
__device__ __forceinline__ float bf2f(unsigned short h) {
  union { unsigned u; float f; } v; v.u = ((unsigned)h) << 16;
  return v.f;
}
// Column-major lower-tri storage with per-column mod-4 alignment:
// column j occupies Lp[cb0f(j)+j .. cb0f(j)+255]; cb0f(j) % 4 == 0 so that
// float4 reads at row i0 (i0%4==0) are 16B-aligned. Total 33280 floats.
__device__ __forceinline__ int cb0f(int j) {
  int m = j & 3;
  return 256 * j - ((j * (j - 1)) >> 1) + 6 * (j >> 2) + ((m * (m + 1)) >> 1) - j;
}

// ---------------- histogram: per-2048-pixel-block label counts, both segs ----
__global__ __launch_bounds__(256) void k_hist(const int* __restrict__ seg_c,
                                              const int* __restrict__ seg_s,
                                              int* __restrict__ hist) {
  __shared__ int h[16];
  int t = threadIdx.x;
  if (t < 16) h[t] = 0;
  __syncthreads();
  int p0 = blockIdx.x * 2048 + t * 8;
#pragma unroll
  for (int e = 0; e < 8; ++e) {
    atomicAdd(&h[seg_c[p0 + e] & 7], 1);
    atomicAdd(&h[8 + (seg_s[p0 + e] & 7)], 1);
  }
  __syncthreads();
  if (t < 8) hist[blockIdx.x * 8 + t] = h[t];
  else if (t < 16) hist[1024 + blockIdx.x * 8 + (t - 8)] = h[t];
}

// ---------------- scan: totals, 512-aligned offsets, per-block bases, valid --
__global__ __launch_bounds__(256) void k_scan(const int* __restrict__ hist,
                                              int* __restrict__ base,
                                              int* __restrict__ off,
                                              int* __restrict__ cnt,
                                              int* __restrict__ valid) {
  __shared__ int lh[2048];
  __shared__ int tot[16];
  __shared__ int loff[2][9];
  int t = threadIdx.x;
  for (int i = t; i < 2048; i += 256) lh[i] = hist[i];
  __syncthreads();
  if (t < 16) {
    int s = t >> 3, l = t & 7, acc = 0;
    for (int b = 0; b < 128; ++b) acc += lh[s * 1024 + b * 8 + l];
    tot[t] = acc;
  }
  __syncthreads();
  if (t < 2) {
    int run = 0;
    for (int l = 0; l < 8; ++l) {
      loff[t][l] = run;
      run = (run + tot[t * 8 + l] + 511) & ~511;
    }
    loff[t][8] = run;
    for (int l = 0; l < 9; ++l) off[t * 9 + l] = loff[t][l];
    for (int l = 0; l < 8; ++l) cnt[t * 8 + l] = tot[t * 8 + l];
  }
  __syncthreads();
  if (t < 8) {
    long nc = tot[t], ns = tot[8 + t];
    valid[t] = (nc > 10 && ns > 10 && nc < 100 * ns && ns < 100 * nc) ? 1 : 0;
  }
  if (t < 16) {
    int s = t >> 3, l = t & 7;
    int run = loff[s][l];
    for (int b = 0; b < 128; ++b) {
      base[s * 1024 + b * 8 + l] = run;
      run += lh[s * 1024 + b * 8 + l];
    }
  }
}

// ---------------- rank: stable per-pixel destination slot (counting sort) ----
__global__ __launch_bounds__(256) void k_rank(const int* __restrict__ seg_c,
                                              const int* __restrict__ seg_s,
                                              const int* __restrict__ base,
                                              int* __restrict__ dst) {
  __shared__ int sc[8 * 272];
  __shared__ int rb[256 * 8];
  __shared__ int bb[8];
  int t = threadIdx.x;
  for (int s = 0; s < 2; ++s) {
    const int* seg = s ? seg_s : seg_c;
    const int* bas = base + s * 1024 + blockIdx.x * 8;
    int* dd = dst + (size_t)s * M_PIX;
    int p0 = blockIdx.x * 2048 + t * 8;
    unsigned pk2 = 0, cpk = 0;
#pragma unroll
    for (int e = 0; e < 8; ++e) {
      int lb = seg[p0 + e] & 7;
      pk2 |= (unsigned)lb << (3 * e);
      cpk += 1u << (4 * lb);
    }
#pragma unroll
    for (int lq = 0; lq < 8; ++lq) sc[lq * 272 + t] = (int)((cpk >> (4 * lq)) & 15u);
    if (t < 8) bb[t] = bas[t];
    __syncthreads();
    for (int d = 1; d < 256; d <<= 1) {
      int v[8];
#pragma unroll
      for (int lq = 0; lq < 8; ++lq)
        v[lq] = sc[lq * 272 + t] + ((t >= d) ? sc[lq * 272 + t - d] : 0);
      __syncthreads();
#pragma unroll
      for (int lq = 0; lq < 8; ++lq) sc[lq * 272 + t] = v[lq];
      __syncthreads();
    }
#pragma unroll
    for (int lq = 0; lq < 8; ++lq)
      rb[t * 8 + lq] = bb[lq] + sc[lq * 272 + t] - (int)((cpk >> (4 * lq)) & 15u);
#pragma unroll
    for (int e = 0; e < 8; ++e) {
      int lb = (int)((pk2 >> (3 * e)) & 7u);
      int dpos = rb[t * 8 + lb]++;
      dd[p0 + e] = dpos;
    }
    __syncthreads();
  }
}

// ---------------- zero the alignment pads of P -------------------------------
__global__ __launch_bounds__(256) void k_padzero(unsigned short* __restrict__ P,
                                                 const int* __restrict__ off,
                                                 const int* __restrict__ cnt) {
  int l = blockIdx.x;
  int c0, c1;
  if (l < 8) { c0 = off[l] + cnt[l]; c1 = off[l + 1]; }
  else       { c0 = off[8];          c1 = MPAD; }
  int w = c1 - c0;
  if (w <= 0) return;
  for (int r = 0; r < 256; ++r)
    for (int cc = threadIdx.x; cc < w; cc += 256)
      P[(size_t)r * MPAD + c0 + cc] = 0;
}

// ---------------- pack: scatter f32 -> packed bf16 (stable order) ------------
__global__ __launch_bounds__(256) void k_pack(const float* __restrict__ feat,
                                              const int* __restrict__ dst,
                                              unsigned short* __restrict__ P) {
  int t = threadIdx.x;
  long p0 = (long)blockIdx.x * 256;
  int d = dst[p0 + t];
  for (int n = 0; n < 256; ++n) {
    float v = feat[(size_t)n * M_PIX + p0 + t];
    P[(size_t)n * MPAD + d] = f2bf(v);
  }
}

// ---------------- per-(label,channel) sums over packed data ------------------
__global__ __launch_bounds__(256) void k_psum(const unsigned short* __restrict__ P,
                                              const int* __restrict__ off,
                                              float* __restrict__ sum) {
  long p0 = (long)blockIdx.x * 512;
  if (p0 >= off[8]) return;
  int l = 0;
  while (l < 7 && p0 >= off[l + 1]) ++l;
  int t = threadIdx.x;
  __shared__ float wsum[4];
#pragma unroll 1
  for (int e = 0; e < 8; ++e) {
    int n = blockIdx.y * 8 + e;
    unsigned v = *(const unsigned*)&P[(size_t)n * MPAD + p0 + 2 * t];
    float f = bf2f((unsigned short)(v & 0xFFFFu)) + bf2f((unsigned short)(v >> 16));
#pragma unroll
    for (int d = 32; d > 0; d >>= 1) f += __shfl_down(f, d, 64);
    if ((t & 63) == 0) wsum[t >> 6] = f;
    __syncthreads();
    if (t == 0) atomicAdd(&sum[l * 256 + n], wsum[0] + wsum[1] + wsum[2] + wsum[3]);
    __syncthreads();
  }
}

// ---------------- Gram: G_l += P_l P_l^T  (bf16 MFMA, lower quadrants) -------
__global__ __launch_bounds__(256) void k_gram(const unsigned short* __restrict__ P,
                                              const int* __restrict__ off,
                                              float* __restrict__ G) {
  int l = blockIdx.y;
  long o0 = off[l], o1 = off[l + 1];
  long k0 = o0 + (long)blockIdx.x * 1024;
  if (k0 >= o1) return;
  long rem = o1 - k0;
  int ks = rem > 1024 ? 1024 : (int)rem;     // always a multiple of 512
  int qi = (blockIdx.z == 0) ? 0 : 1;
  int qj = (blockIdx.z == 2) ? 1 : 0;

  __shared__ unsigned short As[128 * LDA];
  __shared__ unsigned short Bs[128 * LDA];

  int t = threadIdx.x;
  int wave = t >> 6, lane = t & 63;
  int wr = (wave >> 1) * 64, wc = (wave & 1) * 64;

  f32x4 acc[4][4] = {};

  for (int kk = 0; kk < ks; kk += 32) {
#pragma unroll
    for (int it = 0; it < 2; ++it) {
      int slot = t + it * 256;
      int rr = slot >> 2, gg = slot & 3;
      *(uint4*)&As[rr * LDA + gg * 8] =
          *(const uint4*)&P[(size_t)(qi * 128 + rr) * MPAD + (size_t)(k0 + kk) + gg * 8];
      *(uint4*)&Bs[rr * LDA + gg * 8] =
          *(const uint4*)&P[(size_t)(qj * 128 + rr) * MPAD + (size_t)(k0 + kk) + gg * 8];
    }
    __syncthreads();
    bf16x8 bfr[4];
#pragma unroll
    for (int fj = 0; fj < 4; ++fj)
      bfr[fj] = *(const bf16x8*)&Bs[(wc + fj * 16 + (lane & 15)) * LDA + (lane >> 4) * 8];
#pragma unroll
    for (int fi = 0; fi < 4; ++fi) {
      bf16x8 afr = *(const bf16x8*)&As[(wr + fi * 16 + (lane & 15)) * LDA + (lane >> 4) * 8];
#pragma unroll
      for (int fj = 0; fj < 4; ++fj)
        acc[fi][fj] = __builtin_amdgcn_mfma_f32_16x16x32_bf16(afr, bfr[fj], acc[fi][fj], 0, 0, 0);
    }
    __syncthreads();
  }
  float* Gl = G + ((size_t)l << 16);
  int rb = qi * 128 + wr, cb = qj * 128 + wc;
#pragma unroll
  for (int fi = 0; fi < 4; ++fi)
#pragma unroll
    for (int fj = 0; fj < 4; ++fj) {
      int cc = cb + fj * 16 + (lane & 15);
#pragma unroll
      for (int rg = 0; rg < 4; ++rg) {
        int rr = rb + fi * 16 + (lane >> 4) * 4 + rg;
        atomicAdd(&Gl[rr * 256 + cc], acc[fi][fj][rg]);
      }
    }
}

// ---------------- cov = (G - n*mu*mu^T)/(n-1), lower triangle in place -------
__global__ __launch_bounds__(256) void k_cov(float* __restrict__ G,
                                             const float* __restrict__ sum,
                                             const int* __restrict__ cnt,
                                             float* __restrict__ means) {
  int bid = blockIdx.x;                       // side*8 + l
  float* A = G + ((size_t)bid << 16);
  int t = threadIdx.x;
  __shared__ float mu[256];
  float fc = (float)cnt[bid];
  float m = sum[bid * 256 + t] / fmaxf(fc, 1.0f);
  mu[t] = m;
  means[bid * 256 + t] = m;
  __syncthreads();
  float rdiv = 1.0f / fmaxf(fmaxf(fc, 1.0f) - 1.0f, 1.0f);
  float mt = mu[t];
  for (int i = t; i < 256; ++i) {             // lower triangle only
    float g = A[i * 256 + t];
    A[i * 256 + t] = (g - fc * mu[i] * mt) * rdiv;
  }
}

// ---------------- blocked Cholesky, chain-free + conflict-free ---------------
// Per 32-panel: (1) wave 0 factors diag in registers via shfl AND computes the
// explicit inverse W = L11^{-1} (also shfl, independent dots) -> LDS + global;
// (2) L21 = A21 * W^T as independent dot products (broadcast LDS reads only);
// (3) trailing update with wave-per-tile-row, lane-per-tile-col: pi broadcast
// float4, pj lane-consecutive float4 -- the two conflict-free LDS patterns.
__global__ __launch_bounds__(512) void k_chol(float* __restrict__ G,
                                              float* __restrict__ Wg) {
  float* A = G + ((size_t)blockIdx.x << 16);
  __shared__ float Lp[33280];
  __shared__ float Wl[32 * 36];
  int t = threadIdx.x;
  int wave = t >> 6, lane = t & 63;
  int th = t & 255, ih = t >> 8;

  for (int i = ih; i < 256; i += 2)
    if (th <= i) Lp[cb0f(th) + i] = A[i * 256 + th];
  __syncthreads();

#pragma unroll 1
  for (int pb = 0; pb < 8; ++pb) {
    int jbase = pb * 32;
    int H2 = 224 - jbase;                    // trailing height

    // ---- wave 0: factor 32x32 diag + inverse W, all in registers ----
    if (t < 64) {
      int l32 = t & 31;
      float x[32];
#pragma unroll
      for (int k = 0; k < 32; ++k)
        x[k] = (k <= l32) ? Lp[cb0f(jbase + k) + jbase + l32] : 0.0f;
#pragma unroll
      for (int j = 0; j < 32; ++j) {
        float dj = __shfl(x[j], j, 64);
        float rd = 1.0f / sqrtf(dj);
        float lj = x[j] * rd;
        x[j] = lj;
#pragma unroll
        for (int k = j + 1; k < 32; ++k) {
          float lkj = __shfl(lj, k, 64);
          x[k] -= lj * lkj;
        }
      }
      if (t < 32) {
#pragma unroll
        for (int k = 0; k < 32; ++k)
          if (k <= l32) Lp[cb0f(jbase + k) + jbase + l32] = x[k];
      }
      // inverse: lane l32 computes column l32 of W (solve L w = e_l32)
      float w[32];
#pragma unroll
      for (int k = 0; k < 32; ++k) w[k] = 0.0f;
#pragma unroll
      for (int i2 = 0; i2 < 32; ++i2) {
        float s = (i2 == l32) ? 1.0f : 0.0f;
#pragma unroll
        for (int k = 0; k < 32; ++k)
          if (k < i2) s -= __shfl(x[k], i2, 64) * w[k];
        float Lii = __shfl(x[i2], i2, 64);
        float wv = s / Lii;
        w[i2] = (i2 >= l32) ? wv : 0.0f;
      }
      if (t < 32) {
        float* Wgp = Wg + (((size_t)blockIdx.x * 8 + pb) << 10);
#pragma unroll
        for (int i2 = 0; i2 < 32; ++i2)
          if (i2 >= l32) {
            Wl[i2 * 36 + l32] = w[i2];
            Wgp[i2 * 32 + l32] = w[i2];
          }
      }
    }
    __syncthreads();

    // ---- L21 = A21 * W^T : independent dots, broadcast reads ----
    if (t < H2) {
      int r = jbase + 32 + t;
      float a[32];
#pragma unroll
      for (int k = 0; k < 32; ++k) a[k] = Lp[cb0f(jbase + k) + r];
#pragma unroll
      for (int j = 0; j < 32; ++j) {
        float s = 0.0f;
#pragma unroll
        for (int k = 0; k < 32; ++k)
          if (k <= j) s += a[k] * Wl[j * 36 + k];
        Lp[cb0f(jbase + j) + r] = s;
      }
    }
    __syncthreads();

    // ---- trailing update: A22 -= L21 * L21^T ----
    if (H2 > 0) {
      int nts = H2 >> 2;
      int cbp[32];
#pragma unroll
      for (int jl = 0; jl < 32; ++jl) cbp[jl] = cb0f(jbase + jl);
#pragma unroll 1
      for (int ti = wave; ti < nts; ti += 8) {
        bool act = (lane <= ti);
        int tj = act ? lane : ti;
        int i0 = jbase + 32 + ti * 4;
        int j0 = jbase + 32 + tj * 4;
        float4 a0 = {0,0,0,0}, a1 = {0,0,0,0}, a2 = {0,0,0,0}, a3 = {0,0,0,0};
#pragma unroll
        for (int jl = 0; jl < 32; ++jl) {
          float4 pi = *(const float4*)&Lp[cbp[jl] + i0];   // wave-broadcast
          float4 pj = *(const float4*)&Lp[cbp[jl] + j0];   // lane-consecutive
          a0.x += pi.x * pj.x; a0.y += pi.y * pj.x; a0.z += pi.z * pj.x; a0.w += pi.w * pj.x;
          a1.x += pi.x * pj.y; a1.y += pi.y * pj.y; a1.z += pi.z * pj.y; a1.w += pi.w * pj.y;
          a2.x += pi.x * pj.z; a2.y += pi.y * pj.z; a2.z += pi.z * pj.z; a2.w += pi.w * pj.z;
          a3.x += pi.x * pj.w; a3.y += pi.y * pj.w; a3.z += pi.z * pj.w; a3.w += pi.w * pj.w;
        }
        if (act) {
#define WCOL(c, av)                                                             \
          { int jg = j0 + c;                                                    \
            float* pc = &Lp[cb0f(jg) + i0];                                     \
            if (lane < ti) {                                                    \
              float4 v = *(float4*)pc;                                          \
              v.x -= av.x; v.y -= av.y; v.z -= av.z; v.w -= av.w;               \
              *(float4*)pc = v;                                                 \
            } else {                                                            \
              if (i0 + 0 >= jg) pc[0] -= av.x;                                  \
              if (i0 + 1 >= jg) pc[1] -= av.y;                                  \
              if (i0 + 2 >= jg) pc[2] -= av.z;                                  \
              if (i0 + 3 >= jg) pc[3] -= av.w;                                  \
            } }
          WCOL(0, a0) WCOL(1, a1) WCOL(2, a2) WCOL(3, a3)
#undef WCOL
        }
      }
    }
    __syncthreads();
  }

  for (int j = ih; j < 256; j += 2) {         // write L col-major: A[j*256+i]
    int bse = cb0f(j);
    for (int e = th; e < 256 - j; e += 256) A[j * 256 + j + e] = Lp[bse + j + e];
  }
}

// ---------------- T = Ls * Lc^{-1}: blocked right-looking solve --------------
// Panel solve = r . W (independent dots vs the precomputed panel inverse W
// from k_chol) -- no serial recurrence. Trailing update in registers.
#define RQ_INIT(q, rq)                                                          \
  _Pragma("unroll") for (int kl = 0; kl < 32; ++kl) {                           \
    int kg = h * 128 + q * 32 + kl;                                             \
    rq[kl] = (i >= kg) ? Ls[(size_t)kg * 256 + i] : 0.0f;                       \
  }

#define SOLVE_QW(rq)                                                            \
  _Pragma("unroll") for (int jl = 0; jl < 32; ++jl) {                           \
    float s = 0.0f;                                                             \
    _Pragma("unroll") for (int kl = 0; kl < 32; ++kl)                           \
      if (kl >= jl) s += rq[kl] * Wp[kl * 36 + jl];                             \
    Tp[i * 33 + jl] = s;                                                        \
  }

#define P2Q(q, rq)                                                              \
  if ((h * 128 + q * 32 + 32) <= jbase) {                                       \
    _Pragma("unroll") for (int kg = 0; kg < 8; ++kg) {                          \
      _Pragma("unroll") for (int jl = 0; jl < 32; ++jl) {                       \
        const float4 lc =                                                       \
            *(const float4*)&LcRows[jl * 260 + h * 128 + q * 32 + kg * 4];      \
        rq[kg * 4 + 0] -= tv[jl] * lc.x;                                        \
        rq[kg * 4 + 1] -= tv[jl] * lc.y;                                        \
        rq[kg * 4 + 2] -= tv[jl] * lc.z;                                        \
        rq[kg * 4 + 3] -= tv[jl] * lc.w;                                        \
      }                                                                         \
    }                                                                           \
  }

__global__ __launch_bounds__(512) void k_T(const float* __restrict__ G,
                                           const float* __restrict__ Wg,
                                           const float* __restrict__ means,
                                           const int* __restrict__ valid,
                                           unsigned short* __restrict__ Tb,
                                           float* __restrict__ bvec) {
  int l = blockIdx.x;
  int t = threadIdx.x;
  unsigned short* Tbl = Tb + ((size_t)l << 16);
  if (!valid[l]) {
    for (int x = t; x < 65536; x += 512) {
      int rr = x >> 8, cc = x & 255;
      Tbl[x] = f2bf(rr == cc ? 1.0f : 0.0f);
    }
    if (t < 256) bvec[l * 256 + t] = 0.0f;
    return;
  }
  const float* Lc = G + ((size_t)l << 16);        // content L, col-major lower
  const float* Ls = G + ((size_t)(8 + l) << 16);  // style L, col-major lower

  __shared__ float Tp[256 * 33];
  __shared__ float LcRows[32 * 260];
  __shared__ float Wp[32 * 36];
  __shared__ float muc[256];

  int i = t & 255, h = t >> 8;

  if (t < 256) muc[t] = means[l * 256 + t];

  float r0[32], r1[32], r2[32], r3[32];
  RQ_INIT(0, r0) RQ_INIT(1, r1) RQ_INIT(2, r2) RQ_INIT(3, r3)
  float bacc = 0.0f;

#pragma unroll 1
  for (int jb = 7; jb >= 0; --jb) {
    int jbase = jb * 32;
    __syncthreads();                              // protect LDS from prev readers
    for (int idx = t; idx < 32 * 256; idx += 512) {
      int c = idx >> 5, jl = idx & 31;
      int j = jbase + jl;
      LcRows[jl * 260 + c] = (c <= j) ? Lc[(size_t)c * 256 + j] : 0.0f;
    }
    for (int idx = t; idx < 1024; idx += 512)
      Wp[(idx >> 5) * 36 + (idx & 31)] = Wg[(((size_t)l * 8 + jb) << 10) + idx];
    __syncthreads();

    // panel solve in owner half's registers (independent dots vs W)
    if (h == (jb >> 2)) {
      int q = jb & 3;
      if (q == 0) { SOLVE_QW(r0) }
      else if (q == 1) { SOLVE_QW(r1) }
      else if (q == 2) { SOLVE_QW(r2) }
      else { SOLVE_QW(r3) }
    }
    __syncthreads();

#pragma unroll
    for (int e = 0; e < 16; ++e) {
      int jl = h * 16 + e;
      Tbl[(size_t)i * 256 + jbase + jl] = f2bf(Tp[i * 33 + jl]);
    }
    if (h == 0) {
#pragma unroll
      for (int jl = 0; jl < 32; ++jl) bacc += Tp[i * 33 + jl] * muc[jbase + jl];
    }

    // trailing register update  r -= Tpanel * LcRows
    float tv[32];
#pragma unroll
    for (int jl = 0; jl < 32; ++jl) tv[jl] = Tp[i * 33 + jl];
    P2Q(0, r0) P2Q(1, r1) P2Q(2, r2) P2Q(3, r3)
  }

  if (h == 0) bvec[l * 256 + i] = means[(8 + l) * 256 + i] - bacc;
}

// ---------------- out = T_l * x + b_l on packed pixels (in place in P) -------
__global__ __launch_bounds__(256) void k_outgemm(unsigned short* __restrict__ P,
                                                 const unsigned short* __restrict__ Tb,
                                                 const float* __restrict__ bvec,
                                                 const int* __restrict__ off) {
  long px0 = (long)blockIdx.x * 128;
  if (px0 >= off[8]) return;
  int l = 0;
  while (l < 7 && px0 >= off[l + 1]) ++l;
  const unsigned short* Tl = Tb + ((size_t)l << 16);

  __shared__ unsigned short As[256 * LDA];
  __shared__ unsigned short Bs[128 * LDA];
  __shared__ float bsh[256];

  int t = threadIdx.x, wave = t >> 6, lane = t & 63;
  int wrow = wave * 64;
  bsh[t] = bvec[l * 256 + t];

  f32x4 acc[4][8] = {};

  for (int kk = 0; kk < 256; kk += 32) {
#pragma unroll
    for (int it = 0; it < 4; ++it) {            // A: 256 rows x 32 k
      int slot = t + it * 256;
      int rr = slot >> 2, gg = slot & 3;
      *(uint4*)&As[rr * LDA + gg * 8] = *(const uint4*)&Tl[rr * 256 + kk + gg * 8];
    }
#pragma unroll
    for (int it = 0; it < 2; ++it) {            // B: transpose-stage 32k x 128px
      int slot = t + it * 256;
      int pg = slot & 15, kr = slot >> 4;
      uint4 v = *(const uint4*)&P[(size_t)(kk + kr) * MPAD + px0 + pg * 8];
      const unsigned short* vs = (const unsigned short*)&v;
      int krs = kr ^ ((pg & 3) << 3);           // k-block XOR swizzle (bank spread)
#pragma unroll
      for (int e = 0; e < 8; ++e) Bs[(pg * 8 + e) * LDA + krs] = vs[e];
    }
    __syncthreads();
    if (kk < wrow + 64) {                       // T is lower-triangular: skip dead k-tiles
      bf16x8 bfr[8];
#pragma unroll
      for (int fj = 0; fj < 8; ++fj) {
        int px = fj * 16 + (lane & 15);
        int gs = (lane >> 4) ^ ((px >> 3) & 3);
        bfr[fj] = *(const bf16x8*)&Bs[px * LDA + gs * 8];
      }
#pragma unroll
      for (int fi = 0; fi < 4; ++fi) {
        if (wrow + fi * 16 + 15 >= kk) {
          bf16x8 afr = *(const bf16x8*)&As[(wrow + fi * 16 + (lane & 15)) * LDA + (lane >> 4) * 8];
#pragma unroll
          for (int fj = 0; fj < 8; ++fj)
            acc[fi][fj] = __builtin_amdgcn_mfma_f32_16x16x32_bf16(afr, bfr[fj], acc[fi][fj], 0, 0, 0);
        }
      }
    }
    __syncthreads();
  }
#pragma unroll
  for (int fi = 0; fi < 4; ++fi)
#pragma unroll
    for (int fj = 0; fj < 8; ++fj) {
      long p = px0 + fj * 16 + (lane & 15);
#pragma unroll
      for (int rg = 0; rg < 4; ++rg) {
        int rr = wrow + fi * 16 + (lane >> 4) * 4 + rg;
        float v = acc[fi][fj][rg] + bsh[rr];
        P[(size_t)rr * MPAD + p] = f2bf(v);
      }
    }
}

// ---------------- unpack: gather packed bf16 result -> f32 output ------------
__global__ __launch_bounds__(256) void k_unpack(const unsigned short* __restrict__ P,
                                                const int* __restrict__ dst,
                                                float* __restrict__ out) {
  int t = threadIdx.x;
  long p0 = (long)blockIdx.x * 256;
  int d = dst[p0 + t];
  for (int n = 0; n < 256; ++n)
    out[(size_t)n * M_PIX + p0 + t] = bf2f(P[(size_t)n * MPAD + d]);
}

// =============================================================================
extern "C" void kernel_launch(void* const* d_in, const int* in_sizes, int n_in,
                              void* d_out, int out_size, void* d_ws, size_t ws_size,
                              hipStream_t stream) {
  const float* cfeat = (const float*)d_in[0];
  const float* sfeat = (const float*)d_in[1];
  const int* seg_c   = (const int*)d_in[2];
  const int* seg_s   = (const int*)d_in[3];

  char* ws = (char*)d_ws;
  size_t o = 0;
  auto take = [&](size_t b) { size_t r = o; o += (b + 255) & ~(size_t)255; return r; };

  unsigned short* P  = (unsigned short*)(ws + take((size_t)NCH * MPAD * 2));
  size_t zero_b = o;
  float* G           = (float*)(ws + take((size_t)2 * 8 * 65536 * 4));
  float* sum         = (float*)(ws + take((size_t)2 * 8 * 256 * 4));
  int*   hist        = (int*)(ws + take((size_t)2 * 128 * 8 * 4));
  size_t zero_e = o;
  unsigned short* Tb = (unsigned short*)(ws + take((size_t)8 * 65536 * 2));
  float* Wg          = (float*)(ws + take((size_t)16 * 8 * 1024 * 4));
  int*   dst         = (int*)(ws + take((size_t)2 * M_PIX * 4));
  float* means       = (float*)(ws + take((size_t)2 * 8 * 256 * 4));
  float* bvec        = (float*)(ws + take((size_t)8 * 256 * 4));
  int*   base        = (int*)(ws + take((size_t)2 * 128 * 8 * 4));
  int*   off         = (int*)(ws + take((size_t)2 * 9 * 4));
  int*   cnt         = (int*)(ws + take((size_t)2 * 8 * 4));
  int*   valid       = (int*)(ws + take((size_t)8 * 4));
  (void)ws_size; (void)n_in; (void)in_sizes; (void)out_size;

  hipMemsetAsync(ws + zero_b, 0, zero_e - zero_b, stream);

  k_hist<<<dim3(128), dim3(256), 0, stream>>>(seg_c, seg_s, hist);
  k_scan<<<dim3(1), dim3(256), 0, stream>>>(hist, base, off, cnt, valid);
  k_rank<<<dim3(128), dim3(256), 0, stream>>>(seg_c, seg_s, base, dst);

  // style (side 1) first, then content (side 0); P is reused, stream-serial.
  for (int s = 1; s >= 0; --s) {
    const float* feat = s ? sfeat : cfeat;
    k_padzero<<<dim3(9), dim3(256), 0, stream>>>(P, off + s * 9, cnt + s * 8);
    k_pack<<<dim3(1024), dim3(256), 0, stream>>>(feat, dst + (size_t)s * M_PIX, P);
    k_psum<<<dim3(520, 32), dim3(256), 0, stream>>>(P, off + s * 9, sum + (size_t)s * 8 * 256);
    k_gram<<<dim3(260, 8, 3), dim3(256), 0, stream>>>(P, off + s * 9, G + (size_t)s * 8 * 65536);
  }

  k_cov<<<dim3(16), dim3(256), 0, stream>>>(G, sum, cnt, means);
  k_chol<<<dim3(16), dim3(512), 0, stream>>>(G, Wg);
  k_T<<<dim3(8), dim3(512), 0, stream>>>(G, Wg, means, valid, Tb, bvec);
  k_outgemm<<<dim3(2080), dim3(256), 0, stream>>>(P, Tb, bvec, off);
  k_unpack<<<dim3(1024), dim3(256), 0, stream>>>(P, dst, (float*)d_out);
}

// Round 6
// 1500.132 us; speedup vs baseline: 1.4043x; 1.4043x over previous
//
#include <hip/hip_runtime.h>

#define NCH   256
#define M_PIX 262144
#define MPAD  266240   // 520*512 ; >= M_PIX + 8*512 worst-case alignment pad
#define LDA   40       // padded LDS leading dim (bf16 elements) for 32-wide k tiles

typedef short bf16x8 __attribute__((ext_vector_type(8)));
typedef float f32x4  __attribute__((ext_vector_type(4)));

__device__ __forceinline__ unsigned short f2bf(float f) {
  union { float f; unsigned u; } v; v.f = f;
  unsigned r = v.u + 0x7FFFu + ((v.u >> 16) & 1u);
  return (unsigned short)(r >> 16);
}
__device__ __forceinline__ float bf2f(unsigned short h) {
  union { unsigned u; float f; } v; v.u = ((unsigned)h) << 16;
  return v.f;
}

// ---------------- histogram: per-2048-pixel-block label counts, both segs ----
__global__ __launch_bounds__(256) void k_hist(const int* __restrict__ seg_c,
                                              const int* __restrict__ seg_s,
                                              int* __restrict__ hist) {
  __shared__ int h[16];
  int t = threadIdx.x;
  if (t < 16) h[t] = 0;
  __syncthreads();
  int p0 = blockIdx.x * 2048 + t * 8;
#pragma unroll
  for (int e = 0; e < 8; ++e) {
    atomicAdd(&h[seg_c[p0 + e] & 7], 1);
    atomicAdd(&h[8 + (seg_s[p0 + e] & 7)], 1);
  }
  __syncthreads();
  if (t < 8) hist[blockIdx.x * 8 + t] = h[t];
  else if (t < 16) hist[1024 + blockIdx.x * 8 + (t - 8)] = h[t];
}

// ---------------- scan: totals, 512-aligned offsets, per-block bases, valid --
__global__ __launch_bounds__(256) void k_scan(const int* __restrict__ hist,
                                              int* __restrict__ base,
                                              int* __restrict__ off,
                                              int* __restrict__ cnt,
                                              int* __restrict__ valid) {
  __shared__ int lh[2048];
  __shared__ int tot[16];
  __shared__ int loff[2][9];
  int t = threadIdx.x;
  for (int i = t; i < 2048; i += 256) lh[i] = hist[i];
  __syncthreads();
  if (t < 16) {
    int s = t >> 3, l = t & 7, acc = 0;
    for (int b = 0; b < 128; ++b) acc += lh[s * 1024 + b * 8 + l];
    tot[t] = acc;
  }
  __syncthreads();
  if (t < 2) {
    int run = 0;
    for (int l = 0; l < 8; ++l) {
      loff[t][l] = run;
      run = (run + tot[t * 8 + l] + 511) & ~511;
    }
    loff[t][8] = run;
    for (int l = 0; l < 9; ++l) off[t * 9 + l] = loff[t][l];
    for (int l = 0; l < 8; ++l) cnt[t * 8 + l] = tot[t * 8 + l];
  }
  __syncthreads();
  if (t < 8) {
    long nc = tot[t], ns = tot[8 + t];
    valid[t] = (nc > 10 && ns > 10 && nc < 100 * ns && ns < 100 * nc) ? 1 : 0;
  }
  if (t < 16) {
    int s = t >> 3, l = t & 7;
    int run = loff[s][l];
    for (int b = 0; b < 128; ++b) {
      base[s * 1024 + b * 8 + l] = run;
      run += lh[s * 1024 + b * 8 + l];
    }
  }
}

// ---------------- rank: stable per-pixel destination slot (counting sort) ----
__global__ __launch_bounds__(256) void k_rank(const int* __restrict__ seg_c,
                                              const int* __restrict__ seg_s,
                                              const int* __restrict__ base,
                                              int* __restrict__ dst) {
  __shared__ int sc[8 * 272];
  __shared__ int rb[256 * 8];
  __shared__ int bb[8];
  int t = threadIdx.x;
  for (int s = 0; s < 2; ++s) {
    const int* seg = s ? seg_s : seg_c;
    const int* bas = base + s * 1024 + blockIdx.x * 8;
    int* dd = dst + (size_t)s * M_PIX;
    int p0 = blockIdx.x * 2048 + t * 8;
    unsigned pk2 = 0, cpk = 0;
#pragma unroll
    for (int e = 0; e < 8; ++e) {
      int lb = seg[p0 + e] & 7;
      pk2 |= (unsigned)lb << (3 * e);
      cpk += 1u << (4 * lb);
    }
#pragma unroll
    for (int lq = 0; lq < 8; ++lq) sc[lq * 272 + t] = (int)((cpk >> (4 * lq)) & 15u);
    if (t < 8) bb[t] = bas[t];
    __syncthreads();
    for (int d = 1; d < 256; d <<= 1) {
      int v[8];
#pragma unroll
      for (int lq = 0; lq < 8; ++lq)
        v[lq] = sc[lq * 272 + t] + ((t >= d) ? sc[lq * 272 + t - d] : 0);
      __syncthreads();
#pragma unroll
      for (int lq = 0; lq < 8; ++lq) sc[lq * 272 + t] = v[lq];
      __syncthreads();
    }
#pragma unroll
    for (int lq = 0; lq < 8; ++lq)
      rb[t * 8 + lq] = bb[lq] + sc[lq * 272 + t] - (int)((cpk >> (4 * lq)) & 15u);
#pragma unroll
    for (int e = 0; e < 8; ++e) {
      int lb = (int)((pk2 >> (3 * e)) & 7u);
      int dpos = rb[t * 8 + lb]++;
      dd[p0 + e] = dpos;
    }
    __syncthreads();
  }
}

// ---------------- zero the alignment pads of P -------------------------------
__global__ __launch_bounds__(256) void k_padzero(unsigned short* __restrict__ P,
                                                 const int* __restrict__ off,
                                                 const int* __restrict__ cnt) {
  int l = blockIdx.x;
  int c0, c1;
  if (l < 8) { c0 = off[l] + cnt[l]; c1 = off[l + 1]; }
  else       { c0 = off[8];          c1 = MPAD; }
  int w = c1 - c0;
  if (w <= 0) return;
  for (int r = 0; r < 256; ++r)
    for (int cc = threadIdx.x; cc < w; cc += 256)
      P[(size_t)r * MPAD + c0 + cc] = 0;
}

// ---------------- pack: scatter f32 -> packed bf16 (stable order) ------------
__global__ __launch_bounds__(256) void k_pack(const float* __restrict__ feat,
                                              const int* __restrict__ dst,
                                              unsigned short* __restrict__ P) {
  int t = threadIdx.x;
  long p0 = (long)blockIdx.x * 256;
  int d = dst[p0 + t];
  for (int n = 0; n < 256; ++n) {
    float v = feat[(size_t)n * M_PIX + p0 + t];
    P[(size_t)n * MPAD + d] = f2bf(v);
  }
}

// ---------------- per-(label,channel) sums over packed data ------------------
__global__ __launch_bounds__(256) void k_psum(const unsigned short* __restrict__ P,
                                              const int* __restrict__ off,
                                              float* __restrict__ sum) {
  long p0 = (long)blockIdx.x * 512;
  if (p0 >= off[8]) return;
  int l = 0;
  while (l < 7 && p0 >= off[l + 1]) ++l;
  int t = threadIdx.x;
  __shared__ float wsum[4];
#pragma unroll 1
  for (int e = 0; e < 8; ++e) {
    int n = blockIdx.y * 8 + e;
    unsigned v = *(const unsigned*)&P[(size_t)n * MPAD + p0 + 2 * t];
    float f = bf2f((unsigned short)(v & 0xFFFFu)) + bf2f((unsigned short)(v >> 16));
#pragma unroll
    for (int d = 32; d > 0; d >>= 1) f += __shfl_down(f, d, 64);
    if ((t & 63) == 0) wsum[t >> 6] = f;
    __syncthreads();
    if (t == 0) atomicAdd(&sum[l * 256 + n], wsum[0] + wsum[1] + wsum[2] + wsum[3]);
    __syncthreads();
  }
}

// ---------------- Gram: G_l += P_l P_l^T  (bf16 MFMA, lower quadrants) -------
__global__ __launch_bounds__(256) void k_gram(const unsigned short* __restrict__ P,
                                              const int* __restrict__ off,
                                              float* __restrict__ G) {
  int l = blockIdx.y;
  long o0 = off[l], o1 = off[l + 1];
  long k0 = o0 + (long)blockIdx.x * 1024;
  if (k0 >= o1) return;
  long rem = o1 - k0;
  int ks = rem > 1024 ? 1024 : (int)rem;     // always a multiple of 512
  int qi = (blockIdx.z == 0) ? 0 : 1;
  int qj = (blockIdx.z == 2) ? 1 : 0;

  __shared__ unsigned short As[128 * LDA];
  __shared__ unsigned short Bs[128 * LDA];

  int t = threadIdx.x;
  int wave = t >> 6, lane = t & 63;
  int wr = (wave >> 1) * 64, wc = (wave & 1) * 64;

  f32x4 acc[4][4] = {};

  for (int kk = 0; kk < ks; kk += 32) {
#pragma unroll
    for (int it = 0; it < 2; ++it) {
      int slot = t + it * 256;
      int rr = slot >> 2, gg = slot & 3;
      *(uint4*)&As[rr * LDA + gg * 8] =
          *(const uint4*)&P[(size_t)(qi * 128 + rr) * MPAD + (size_t)(k0 + kk) + gg * 8];
      *(uint4*)&Bs[rr * LDA + gg * 8] =
          *(const uint4*)&P[(size_t)(qj * 128 + rr) * MPAD + (size_t)(k0 + kk) + gg * 8];
    }
    __syncthreads();
    bf16x8 bfr[4];
#pragma unroll
    for (int fj = 0; fj < 4; ++fj)
      bfr[fj] = *(const bf16x8*)&Bs[(wc + fj * 16 + (lane & 15)) * LDA + (lane >> 4) * 8];
#pragma unroll
    for (int fi = 0; fi < 4; ++fi) {
      bf16x8 afr = *(const bf16x8*)&As[(wr + fi * 16 + (lane & 15)) * LDA + (lane >> 4) * 8];
#pragma unroll
      for (int fj = 0; fj < 4; ++fj)
        acc[fi][fj] = __builtin_amdgcn_mfma_f32_16x16x32_bf16(afr, bfr[fj], acc[fi][fj], 0, 0, 0);
    }
    __syncthreads();
  }
  float* Gl = G + ((size_t)l << 16);
  int rb = qi * 128 + wr, cb = qj * 128 + wc;
#pragma unroll
  for (int fi = 0; fi < 4; ++fi)
#pragma unroll
    for (int fj = 0; fj < 4; ++fj) {
      int cc = cb + fj * 16 + (lane & 15);
#pragma unroll
      for (int rg = 0; rg < 4; ++rg) {
        int rr = rb + fi * 16 + (lane >> 4) * 4 + rg;
        atomicAdd(&Gl[rr * 256 + cc], acc[fi][fj][rg]);
      }
    }
}

// ---------------- cov: read lower row-major, write TRANSPOSED in place -------
// After this kernel G holds cov in "LT" layout: LT[j*256+i] = cov(i,j), i>=j
// (== col-major lower). Read set (lower) ∩ write set (upper) = diagonal, and
// the diagonal element is read and written by the same thread -> race-free.
__global__ __launch_bounds__(256) void k_cov(float* __restrict__ G,
                                             const float* __restrict__ sum,
                                             const int* __restrict__ cnt,
                                             float* __restrict__ means) {
  int bid = blockIdx.x;                       // side*8 + l
  float* A = G + ((size_t)bid << 16);
  int t = threadIdx.x;
  __shared__ float mu[256];
  float fc = (float)cnt[bid];
  float m = sum[bid * 256 + t] / fmaxf(fc, 1.0f);
  mu[t] = m;
  means[bid * 256 + t] = m;
  __syncthreads();
  float rdiv = 1.0f / fmaxf(fmaxf(fc, 1.0f) - 1.0f, 1.0f);
  float mt = mu[t];
  for (int i = t; i < 256; ++i) {
    float g = A[i * 256 + t];
    A[t * 256 + i] = (g - fc * mu[i] * mt) * rdiv;
  }
}

// ---------------- panel step: factor 32x32 diag + W=L11^{-1} + L21 ----------
// LT layout (col-major lower). One block per matrix; wide-kernel trailing
// update is a separate kernel (k_trail) so the O(n^3) bulk runs on 160 blocks.
__global__ __launch_bounds__(256) void k_panel(float* __restrict__ G,
                                               float* __restrict__ Wg,
                                               int pb) {
  float* LT = G + ((size_t)blockIdx.x << 16);
  int t = threadIdx.x;
  int jbase = pb * 32;
  int H2 = 224 - jbase;
  __shared__ float Wl[32 * 36];

  if (t < 64) {
    int l32 = t & 31;
    float x[32];
#pragma unroll
    for (int k = 0; k < 32; ++k)
      x[k] = (k <= l32) ? LT[(size_t)(jbase + k) * 256 + jbase + l32] : 0.0f;
#pragma unroll
    for (int j = 0; j < 32; ++j) {
      float dj = __shfl(x[j], j, 64);
      float rd = 1.0f / sqrtf(dj);
      float lj = x[j] * rd;
      x[j] = lj;
#pragma unroll
      for (int k = j + 1; k < 32; ++k) {
        float lkj = __shfl(lj, k, 64);
        x[k] -= lj * lkj;
      }
    }
    if (t < 32) {
#pragma unroll
      for (int k = 0; k < 32; ++k)
        if (k <= l32) LT[(size_t)(jbase + k) * 256 + jbase + l32] = x[k];
    }
    // explicit inverse: lane l32 = column l32 of W (solve L w = e_l32)
    float w[32];
#pragma unroll
    for (int k = 0; k < 32; ++k) w[k] = 0.0f;
#pragma unroll
    for (int i2 = 0; i2 < 32; ++i2) {
      float s = (i2 == l32) ? 1.0f : 0.0f;
#pragma unroll
      for (int k = 0; k < 32; ++k)
        if (k < i2) s -= __shfl(x[k], i2, 64) * w[k];
      float Lii = __shfl(x[i2], i2, 64);
      float wv = s / Lii;
      w[i2] = (i2 >= l32) ? wv : 0.0f;
    }
    if (t < 32) {
      float* Wgp = Wg + (((size_t)blockIdx.x * 8 + pb) << 10);
#pragma unroll
      for (int i2 = 0; i2 < 32; ++i2)
        if (i2 >= l32) {
          Wl[i2 * 36 + l32] = w[i2];
          Wgp[i2 * 32 + l32] = w[i2];
        }
    }
  }
  __syncthreads();

  // L21 = A21 * W^T : independent dots, coalesced global reads/writes
  if (t < H2) {
    int r = jbase + 32 + t;
    float a[32];
#pragma unroll
    for (int k = 0; k < 32; ++k) a[k] = LT[(size_t)(jbase + k) * 256 + r];
#pragma unroll
    for (int j = 0; j < 32; ++j) {
      float s = 0.0f;
#pragma unroll
      for (int k = 0; k < 32; ++k)
        if (k <= j) s += a[k] * Wl[j * 36 + k];
      LT[(size_t)(jbase + j) * 256 + r] = s;
    }
  }
}

// ---------------- trailing step: A22 -= L21 * L21^T (wide, 64x64 tiles) ------
__global__ __launch_bounds__(256) void k_trail(float* __restrict__ G, int pb) {
  int jbase = pb * 32;
  int H2 = 224 - jbase;
  int nts2 = (H2 + 63) >> 6;
  int y = blockIdx.y;
  if (y >= (nts2 * (nts2 + 1)) >> 1) return;
  int ti = 0;
  while ((((ti + 1) * (ti + 2)) >> 1) <= y) ++ti;
  int tj = y - ((ti * (ti + 1)) >> 1);
  float* LT = G + ((size_t)blockIdx.x << 16);
  int i0 = jbase + 32 + ti * 64;
  int j0 = jbase + 32 + tj * 64;

  __shared__ float Li[32][64];
  __shared__ float Lj[32][64];
  int t = threadIdx.x;
  for (int idx = t; idx < 2048; idx += 256) {
    int k = idx >> 6, r = idx & 63;
    Li[k][r] = (i0 + r < 256) ? LT[(size_t)(jbase + k) * 256 + i0 + r] : 0.0f;
    Lj[k][r] = (j0 + r < 256) ? LT[(size_t)(jbase + k) * 256 + j0 + r] : 0.0f;
  }
  __syncthreads();

  int tx = t & 15, ty = t >> 4;
  float acc[4][4] = {};
#pragma unroll
  for (int k = 0; k < 32; ++k) {
    float4 a = *(const float4*)&Li[k][ty * 4];
    float4 b = *(const float4*)&Lj[k][tx * 4];
    acc[0][0] += a.x * b.x; acc[0][1] += a.x * b.y; acc[0][2] += a.x * b.z; acc[0][3] += a.x * b.w;
    acc[1][0] += a.y * b.x; acc[1][1] += a.y * b.y; acc[1][2] += a.y * b.z; acc[1][3] += a.y * b.w;
    acc[2][0] += a.z * b.x; acc[2][1] += a.z * b.y; acc[2][2] += a.z * b.z; acc[2][3] += a.z * b.w;
    acc[3][0] += a.w * b.x; acc[3][1] += a.w * b.y; acc[3][2] += a.w * b.z; acc[3][3] += a.w * b.w;
  }
#pragma unroll
  for (int jj = 0; jj < 4; ++jj) {
    int j = j0 + tx * 4 + jj;
    if (j >= 256) continue;
    float* col = &LT[(size_t)j * 256 + i0 + ty * 4];
#pragma unroll
    for (int ii = 0; ii < 4; ++ii) {
      int i = i0 + ty * 4 + ii;
      if (i < 256 && i >= j) col[ii] -= acc[ii][jj];
    }
  }
}

// ---------------- T = Ls * Lc^{-1}: blocked right-looking solve --------------
// Panel solve = r . W (precomputed inverse) -- no serial recurrence.
#define RQ_INIT(q, rq)                                                          \
  _Pragma("unroll") for (int kl = 0; kl < 32; ++kl) {                           \
    int kg = h * 128 + q * 32 + kl;                                             \
    rq[kl] = (i >= kg) ? Ls[(size_t)kg * 256 + i] : 0.0f;                       \
  }

#define SOLVE_QW(rq)                                                            \
  _Pragma("unroll") for (int jl = 0; jl < 32; ++jl) {                           \
    float s = 0.0f;                                                             \
    _Pragma("unroll") for (int kl = 0; kl < 32; ++kl)                           \
      if (kl >= jl) s += rq[kl] * Wp[kl * 36 + jl];                             \
    Tp[i * 33 + jl] = s;                                                        \
  }

#define P2Q(q, rq)                                                              \
  if ((h * 128 + q * 32 + 32) <= jbase) {                                       \
    _Pragma("unroll") for (int kg = 0; kg < 8; ++kg) {                          \
      _Pragma("unroll") for (int jl = 0; jl < 32; ++jl) {                       \
        const float4 lc =                                                       \
            *(const float4*)&LcRows[jl * 260 + h * 128 + q * 32 + kg * 4];      \
        rq[kg * 4 + 0] -= tv[jl] * lc.x;                                        \
        rq[kg * 4 + 1] -= tv[jl] * lc.y;                                        \
        rq[kg * 4 + 2] -= tv[jl] * lc.z;                                        \
        rq[kg * 4 + 3] -= tv[jl] * lc.w;                                        \
      }                                                                         \
    }                                                                           \
  }

__global__ __launch_bounds__(512) void k_T(const float* __restrict__ G,
                                           const float* __restrict__ Wg,
                                           const float* __restrict__ means,
                                           const int* __restrict__ valid,
                                           unsigned short* __restrict__ Tb,
                                           float* __restrict__ bvec) {
  int l = blockIdx.x;
  int t = threadIdx.x;
  unsigned short* Tbl = Tb + ((size_t)l << 16);
  if (!valid[l]) {
    for (int x = t; x < 65536; x += 512) {
      int rr = x >> 8, cc = x & 255;
      Tbl[x] = f2bf(rr == cc ? 1.0f : 0.0f);
    }
    if (t < 256) bvec[l * 256 + t] = 0.0f;
    return;
  }
  const float* Lc = G + ((size_t)l << 16);        // content L, LT (col-major)
  const float* Ls = G + ((size_t)(8 + l) << 16);  // style L, LT (col-major)

  __shared__ float Tp[256 * 33];
  __shared__ float LcRows[32 * 260];
  __shared__ float Wp[32 * 36];
  __shared__ float muc[256];

  int i = t & 255, h = t >> 8;

  if (t < 256) muc[t] = means[l * 256 + t];

  float r0[32], r1[32], r2[32], r3[32];
  RQ_INIT(0, r0) RQ_INIT(1, r1) RQ_INIT(2, r2) RQ_INIT(3, r3)
  float bacc = 0.0f;

#pragma unroll 1
  for (int jb = 7; jb >= 0; --jb) {
    int jbase = jb * 32;
    __syncthreads();                              // protect LDS from prev readers
    for (int idx = t; idx < 32 * 256; idx += 512) {
      int c = idx >> 5, jl = idx & 31;
      int j = jbase + jl;
      LcRows[jl * 260 + c] = (c <= j) ? Lc[(size_t)c * 256 + j] : 0.0f;
    }
    for (int idx = t; idx < 1024; idx += 512)
      Wp[(idx >> 5) * 36 + (idx & 31)] = Wg[(((size_t)l * 8 + jb) << 10) + idx];
    __syncthreads();

    if (h == (jb >> 2)) {
      int q = jb & 3;
      if (q == 0) { SOLVE_QW(r0) }
      else if (q == 1) { SOLVE_QW(r1) }
      else if (q == 2) { SOLVE_QW(r2) }
      else { SOLVE_QW(r3) }
    }
    __syncthreads();

#pragma unroll
    for (int e = 0; e < 16; ++e) {
      int jl = h * 16 + e;
      Tbl[(size_t)i * 256 + jbase + jl] = f2bf(Tp[i * 33 + jl]);
    }
    if (h == 0) {
#pragma unroll
      for (int jl = 0; jl < 32; ++jl) bacc += Tp[i * 33 + jl] * muc[jbase + jl];
    }

    float tv[32];
#pragma unroll
    for (int jl = 0; jl < 32; ++jl) tv[jl] = Tp[i * 33 + jl];
    P2Q(0, r0) P2Q(1, r1) P2Q(2, r2) P2Q(3, r3)
  }

  if (h == 0) bvec[l * 256 + i] = means[(8 + l) * 256 + i] - bacc;
}

// ---------------- out = T_l * x + b_l on packed pixels (in place in P) -------
__global__ __launch_bounds__(256) void k_outgemm(unsigned short* __restrict__ P,
                                                 const unsigned short* __restrict__ Tb,
                                                 const float* __restrict__ bvec,
                                                 const int* __restrict__ off) {
  long px0 = (long)blockIdx.x * 128;
  if (px0 >= off[8]) return;
  int l = 0;
  while (l < 7 && px0 >= off[l + 1]) ++l;
  const unsigned short* Tl = Tb + ((size_t)l << 16);

  __shared__ unsigned short As[256 * LDA];
  __shared__ unsigned short Bs[128 * LDA];
  __shared__ float bsh[256];

  int t = threadIdx.x, wave = t >> 6, lane = t & 63;
  int wrow = wave * 64;
  bsh[t] = bvec[l * 256 + t];

  f32x4 acc[4][8] = {};

  for (int kk = 0; kk < 256; kk += 32) {
#pragma unroll
    for (int it = 0; it < 4; ++it) {            // A: 256 rows x 32 k
      int slot = t + it * 256;
      int rr = slot >> 2, gg = slot & 3;
      *(uint4*)&As[rr * LDA + gg * 8] = *(const uint4*)&Tl[rr * 256 + kk + gg * 8];
    }
#pragma unroll
    for (int it = 0; it < 2; ++it) {            // B: transpose-stage 32k x 128px
      int slot = t + it * 256;
      int pg = slot & 15, kr = slot >> 4;
      uint4 v = *(const uint4*)&P[(size_t)(kk + kr) * MPAD + px0 + pg * 8];
      const unsigned short* vs = (const unsigned short*)&v;
      int krs = kr ^ ((pg & 3) << 3);           // k-block XOR swizzle (bank spread)
#pragma unroll
      for (int e = 0; e < 8; ++e) Bs[(pg * 8 + e) * LDA + krs] = vs[e];
    }
    __syncthreads();
    if (kk < wrow + 64) {                       // T is lower-triangular: skip dead k-tiles
      bf16x8 bfr[8];
#pragma unroll
      for (int fj = 0; fj < 8; ++fj) {
        int px = fj * 16 + (lane & 15);
        int gs = (lane >> 4) ^ ((px >> 3) & 3);
        bfr[fj] = *(const bf16x8*)&Bs[px * LDA + gs * 8];
      }
#pragma unroll
      for (int fi = 0; fi < 4; ++fi) {
        if (wrow + fi * 16 + 15 >= kk) {
          bf16x8 afr = *(const bf16x8*)&As[(wrow + fi * 16 + (lane & 15)) * LDA + (lane >> 4) * 8];
#pragma unroll
          for (int fj = 0; fj < 8; ++fj)
            acc[fi][fj] = __builtin_amdgcn_mfma_f32_16x16x32_bf16(afr, bfr[fj], acc[fi][fj], 0, 0, 0);
        }
      }
    }
    __syncthreads();
  }
#pragma unroll
  for (int fi = 0; fi < 4; ++fi)
#pragma unroll
    for (int fj = 0; fj < 8; ++fj) {
      long p = px0 + fj * 16 + (lane & 15);
#pragma unroll
      for (int rg = 0; rg < 4; ++rg) {
        int rr = wrow + fi * 16 + (lane >> 4) * 4 + rg;
        float v = acc[fi][fj][rg] + bsh[rr];
        P[(size_t)rr * MPAD + p] = f2bf(v);
      }
    }
}

// ---------------- unpack: gather packed bf16 result -> f32 output ------------
__global__ __launch_bounds__(256) void k_unpack(const unsigned short* __restrict__ P,
                                                const int* __restrict__ dst,
                                                float* __restrict__ out) {
  int t = threadIdx.x;
  long p0 = (long)blockIdx.x * 256;
  int d = dst[p0 + t];
  for (int n = 0; n < 256; ++n)
    out[(size_t)n * M_PIX + p0 + t] = bf2f(P[(size_t)n * MPAD + d]);
}

// =============================================================================
extern "C" void kernel_launch(void* const* d_in, const int* in_sizes, int n_in,
                              void* d_out, int out_size, void* d_ws, size_t ws_size,
                              hipStream_t stream) {
  const float* cfeat = (const float*)d_in[0];
  const float* sfeat = (const float*)d_in[1];
  const int* seg_c   = (const int*)d_in[2];
  const int* seg_s   = (const int*)d_in[3];

  char* ws = (char*)d_ws;
  size_t o = 0;
  auto take = [&](size_t b) { size_t r = o; o += (b + 255) & ~(size_t)255; return r; };

  unsigned short* P  = (unsigned short*)(ws + take((size_t)NCH * MPAD * 2));
  size_t zero_b = o;
  float* G           = (float*)(ws + take((size_t)2 * 8 * 65536 * 4));
  float* sum         = (float*)(ws + take((size_t)2 * 8 * 256 * 4));
  int*   hist        = (int*)(ws + take((size_t)2 * 128 * 8 * 4));
  size_t zero_e = o;
  unsigned short* Tb = (unsigned short*)(ws + take((size_t)8 * 65536 * 2));
  float* Wg          = (float*)(ws + take((size_t)16 * 8 * 1024 * 4));
  int*   dst         = (int*)(ws + take((size_t)2 * M_PIX * 4));
  float* means       = (float*)(ws + take((size_t)2 * 8 * 256 * 4));
  float* bvec        = (float*)(ws + take((size_t)8 * 256 * 4));
  int*   base        = (int*)(ws + take((size_t)2 * 128 * 8 * 4));
  int*   off         = (int*)(ws + take((size_t)2 * 9 * 4));
  int*   cnt         = (int*)(ws + take((size_t)2 * 8 * 4));
  int*   valid       = (int*)(ws + take((size_t)8 * 4));
  (void)ws_size; (void)n_in; (void)in_sizes; (void)out_size;

  hipMemsetAsync(ws + zero_b, 0, zero_e - zero_b, stream);

  k_hist<<<dim3(128), dim3(256), 0, stream>>>(seg_c, seg_s, hist);
  k_scan<<<dim3(1), dim3(256), 0, stream>>>(hist, base, off, cnt, valid);
  k_rank<<<dim3(128), dim3(256), 0, stream>>>(seg_c, seg_s, base, dst);

  // style (side 1) first, then content (side 0); P is reused, stream-serial.
  for (int s = 1; s >= 0; --s) {
    const float* feat = s ? sfeat : cfeat;
    k_padzero<<<dim3(9), dim3(256), 0, stream>>>(P, off + s * 9, cnt + s * 8);
    k_pack<<<dim3(1024), dim3(256), 0, stream>>>(feat, dst + (size_t)s * M_PIX, P);
    k_psum<<<dim3(520, 32), dim3(256), 0, stream>>>(P, off + s * 9, sum + (size_t)s * 8 * 256);
    k_gram<<<dim3(260, 8, 3), dim3(256), 0, stream>>>(P, off + s * 9, G + (size_t)s * 8 * 65536);
  }

  k_cov<<<dim3(16), dim3(256), 0, stream>>>(G, sum, cnt, means);
  for (int pb = 0; pb < 8; ++pb) {
    k_panel<<<dim3(16), dim3(256), 0, stream>>>(G, Wg, pb);
    if (pb < 7) k_trail<<<dim3(16, 10), dim3(256), 0, stream>>>(G, pb);
  }
  k_T<<<dim3(8), dim3(512), 0, stream>>>(G, Wg, means, valid, Tb, bvec);
  k_outgemm<<<dim3(2080), dim3(256), 0, stream>>>(P, Tb, bvec, off);
  k_unpack<<<dim3(1024), dim3(256), 0, stream>>>(P, dst, (float*)d_out);
}

// Round 7
// 1307.954 us; speedup vs baseline: 1.6107x; 1.1469x over previous
//
#include <hip/hip_runtime.h>

#define NCH   256
#define M_PIX 262144
#define MPAD  266240   // 520*512 ; >= M_PIX + 8*512 worst-case alignment pad
#define LDA   40       // padded LDS leading dim (bf16 elements) for 32-wide k tiles

typedef short bf16x8 __attribute__((ext_vector_type(8)));
typedef float f32x4  __attribute__((ext_vector_type(4)));

__device__ __forceinline__ unsigned short f2bf(float f) {
  union { float f; unsigned u; } v; v.f = f;
  unsigned r = v.u + 0x7FFFu + ((v.u >> 16) & 1u);
  return (unsigned short)(r >> 16);
}
__device__ __forceinline__ float bf2f(unsigned short h) {
  union { unsigned u; float f; } v; v.u = ((unsigned)h) << 16;
  return v.f;
}

// ---------------- histogram: per-2048-pixel-block label counts, both segs ----
__global__ __launch_bounds__(256) void k_hist(const int* __restrict__ seg_c,
                                              const int* __restrict__ seg_s,
                                              int* __restrict__ hist) {
  __shared__ int h[16];
  int t = threadIdx.x;
  if (t < 16) h[t] = 0;
  __syncthreads();
  int p0 = blockIdx.x * 2048 + t * 8;
#pragma unroll
  for (int e = 0; e < 8; ++e) {
    atomicAdd(&h[seg_c[p0 + e] & 7], 1);
    atomicAdd(&h[8 + (seg_s[p0 + e] & 7)], 1);
  }
  __syncthreads();
  if (t < 8) hist[blockIdx.x * 8 + t] = h[t];
  else if (t < 16) hist[1024 + blockIdx.x * 8 + (t - 8)] = h[t];
}

// ---------------- scan: totals, 512-aligned offsets, per-block bases, valid --
__global__ __launch_bounds__(256) void k_scan(const int* __restrict__ hist,
                                              int* __restrict__ base,
                                              int* __restrict__ off,
                                              int* __restrict__ cnt,
                                              int* __restrict__ valid) {
  __shared__ int lh[2048];
  __shared__ int tot[16];
  __shared__ int loff[2][9];
  int t = threadIdx.x;
  for (int i = t; i < 2048; i += 256) lh[i] = hist[i];
  __syncthreads();
  if (t < 16) {
    int s = t >> 3, l = t & 7, acc = 0;
    for (int b = 0; b < 128; ++b) acc += lh[s * 1024 + b * 8 + l];
    tot[t] = acc;
  }
  __syncthreads();
  if (t < 2) {
    int run = 0;
    for (int l = 0; l < 8; ++l) {
      loff[t][l] = run;
      run = (run + tot[t * 8 + l] + 511) & ~511;
    }
    loff[t][8] = run;
    for (int l = 0; l < 9; ++l) off[t * 9 + l] = loff[t][l];
    for (int l = 0; l < 8; ++l) cnt[t * 8 + l] = tot[t * 8 + l];
  }
  __syncthreads();
  if (t < 8) {
    long nc = tot[t], ns = tot[8 + t];
    valid[t] = (nc > 10 && ns > 10 && nc < 100 * ns && ns < 100 * nc) ? 1 : 0;
  }
  if (t < 16) {
    int s = t >> 3, l = t & 7;
    int run = loff[s][l];
    for (int b = 0; b < 128; ++b) {
      base[s * 1024 + b * 8 + l] = run;
      run += lh[s * 1024 + b * 8 + l];
    }
  }
}

// ---------------- rank: stable per-pixel destination slot (counting sort) ----
__global__ __launch_bounds__(256) void k_rank(const int* __restrict__ seg_c,
                                              const int* __restrict__ seg_s,
                                              const int* __restrict__ base,
                                              int* __restrict__ dst) {
  __shared__ int sc[8 * 272];
  __shared__ int rb[256 * 8];
  __shared__ int bb[8];
  int t = threadIdx.x;
  for (int s = 0; s < 2; ++s) {
    const int* seg = s ? seg_s : seg_c;
    const int* bas = base + s * 1024 + blockIdx.x * 8;
    int* dd = dst + (size_t)s * M_PIX;
    int p0 = blockIdx.x * 2048 + t * 8;
    unsigned pk2 = 0, cpk = 0;
#pragma unroll
    for (int e = 0; e < 8; ++e) {
      int lb = seg[p0 + e] & 7;
      pk2 |= (unsigned)lb << (3 * e);
      cpk += 1u << (4 * lb);
    }
#pragma unroll
    for (int lq = 0; lq < 8; ++lq) sc[lq * 272 + t] = (int)((cpk >> (4 * lq)) & 15u);
    if (t < 8) bb[t] = bas[t];
    __syncthreads();
    for (int d = 1; d < 256; d <<= 1) {
      int v[8];
#pragma unroll
      for (int lq = 0; lq < 8; ++lq)
        v[lq] = sc[lq * 272 + t] + ((t >= d) ? sc[lq * 272 + t - d] : 0);
      __syncthreads();
#pragma unroll
      for (int lq = 0; lq < 8; ++lq) sc[lq * 272 + t] = v[lq];
      __syncthreads();
    }
#pragma unroll
    for (int lq = 0; lq < 8; ++lq)
      rb[t * 8 + lq] = bb[lq] + sc[lq * 272 + t] - (int)((cpk >> (4 * lq)) & 15u);
#pragma unroll
    for (int e = 0; e < 8; ++e) {
      int lb = (int)((pk2 >> (3 * e)) & 7u);
      int dpos = rb[t * 8 + lb]++;
      dd[p0 + e] = dpos;
    }
    __syncthreads();
  }
}

// ---------------- zero the alignment pads of P -------------------------------
__global__ __launch_bounds__(256) void k_padzero(unsigned short* __restrict__ P,
                                                 const int* __restrict__ off,
                                                 const int* __restrict__ cnt) {
  int l = blockIdx.x;
  int c0, c1;
  if (l < 8) { c0 = off[l] + cnt[l]; c1 = off[l + 1]; }
  else       { c0 = off[8];          c1 = MPAD; }
  int w = c1 - c0;
  if (w <= 0) return;
  for (int r = 0; r < 256; ++r)
    for (int cc = threadIdx.x; cc < w; cc += 256)
      P[(size_t)r * MPAD + c0 + cc] = 0;
}

// ---------------- pack: coalesced-both-sides via LDS local sort --------------
// Block = (2048-pixel block b, 32-channel group g). LDS slot of pixel p is
// lbase[label] + (dst[p]-gbase[label]) -- a bijection onto [0,2048). Output
// position q maps to global dst gbase[l(q)] + q - lbase[l(q)], contiguous in q
// within each label run -> wave writes are 128B-coalesced.
__global__ __launch_bounds__(256) void k_pack(const float* __restrict__ feat,
                                              const int* __restrict__ seg,
                                              const int* __restrict__ dst,
                                              const int* __restrict__ base,
                                              unsigned short* __restrict__ P) {
  int b = blockIdx.x, g = blockIdx.y, t = threadIdx.x;
  int p0 = b * 2048;
  __shared__ unsigned short buf[8][2048];
  __shared__ int h[8], lbase[9], gbase[8];
  if (t < 8) { h[t] = 0; gbase[t] = base[b * 8 + t]; }
  __syncthreads();
  int lb[8], slot[8], gd[8];
#pragma unroll
  for (int i = 0; i < 8; ++i) {
    lb[i] = seg[p0 + i * 256 + t] & 7;
    atomicAdd(&h[lb[i]], 1);
  }
  __syncthreads();
  if (t == 0) {
    int run = 0;
    for (int l = 0; l < 8; ++l) { lbase[l] = run; run += h[l]; }
    lbase[8] = run;
  }
  __syncthreads();
#pragma unroll
  for (int i = 0; i < 8; ++i)
    slot[i] = lbase[lb[i]] + (dst[p0 + i * 256 + t] - gbase[lb[i]]);
#pragma unroll
  for (int i = 0; i < 8; ++i) {
    int q = i * 256 + t;
    int l = 0;
    while (l < 7 && q >= lbase[l + 1]) ++l;
    gd[i] = gbase[l] + q - lbase[l];
  }
  int n0 = g * 32;
#pragma unroll 1
  for (int cp = 0; cp < 4; ++cp) {
#pragma unroll
    for (int c = 0; c < 8; ++c) {
      const float* fp = &feat[(size_t)(n0 + cp * 8 + c) * M_PIX + p0];
#pragma unroll
      for (int i = 0; i < 8; ++i)
        buf[c][slot[i]] = f2bf(fp[i * 256 + t]);
    }
    __syncthreads();
#pragma unroll
    for (int c = 0; c < 8; ++c) {
      unsigned short* pp = &P[(size_t)(n0 + cp * 8 + c) * MPAD];
#pragma unroll
      for (int i = 0; i < 8; ++i)
        pp[gd[i]] = buf[c][i * 256 + t];
    }
    __syncthreads();
  }
}

// ---------------- unpack: mirrored (contiguous reads, coalesced f32 writes) --
__global__ __launch_bounds__(256) void k_unpack(const unsigned short* __restrict__ P,
                                                const int* __restrict__ seg,
                                                const int* __restrict__ dst,
                                                const int* __restrict__ base,
                                                float* __restrict__ out) {
  int b = blockIdx.x, g = blockIdx.y, t = threadIdx.x;
  int p0 = b * 2048;
  __shared__ unsigned short buf[8][2048];
  __shared__ int h[8], lbase[9], gbase[8];
  if (t < 8) { h[t] = 0; gbase[t] = base[b * 8 + t]; }
  __syncthreads();
  int lb[8], slot[8], gd[8];
#pragma unroll
  for (int i = 0; i < 8; ++i) {
    lb[i] = seg[p0 + i * 256 + t] & 7;
    atomicAdd(&h[lb[i]], 1);
  }
  __syncthreads();
  if (t == 0) {
    int run = 0;
    for (int l = 0; l < 8; ++l) { lbase[l] = run; run += h[l]; }
    lbase[8] = run;
  }
  __syncthreads();
#pragma unroll
  for (int i = 0; i < 8; ++i)
    slot[i] = lbase[lb[i]] + (dst[p0 + i * 256 + t] - gbase[lb[i]]);
#pragma unroll
  for (int i = 0; i < 8; ++i) {
    int q = i * 256 + t;
    int l = 0;
    while (l < 7 && q >= lbase[l + 1]) ++l;
    gd[i] = gbase[l] + q - lbase[l];
  }
  int n0 = g * 32;
#pragma unroll 1
  for (int cp = 0; cp < 4; ++cp) {
#pragma unroll
    for (int c = 0; c < 8; ++c) {
      const unsigned short* pp = &P[(size_t)(n0 + cp * 8 + c) * MPAD];
#pragma unroll
      for (int i = 0; i < 8; ++i)
        buf[c][i * 256 + t] = pp[gd[i]];
    }
    __syncthreads();
#pragma unroll
    for (int c = 0; c < 8; ++c) {
      float* op = &out[(size_t)(n0 + cp * 8 + c) * M_PIX + p0];
#pragma unroll
      for (int i = 0; i < 8; ++i)
        op[i * 256 + t] = bf2f(buf[c][slot[i]]);
    }
    __syncthreads();
  }
}

// ---------------- per-(label,channel) sums over packed data ------------------
__global__ __launch_bounds__(256) void k_psum(const unsigned short* __restrict__ P,
                                              const int* __restrict__ off,
                                              float* __restrict__ sum) {
  long p0 = (long)blockIdx.x * 512;
  if (p0 >= off[8]) return;
  int l = 0;
  while (l < 7 && p0 >= off[l + 1]) ++l;
  int t = threadIdx.x;
  __shared__ float wsum[4];
#pragma unroll 1
  for (int e = 0; e < 8; ++e) {
    int n = blockIdx.y * 8 + e;
    unsigned v = *(const unsigned*)&P[(size_t)n * MPAD + p0 + 2 * t];
    float f = bf2f((unsigned short)(v & 0xFFFFu)) + bf2f((unsigned short)(v >> 16));
#pragma unroll
    for (int d = 32; d > 0; d >>= 1) f += __shfl_down(f, d, 64);
    if ((t & 63) == 0) wsum[t >> 6] = f;
    __syncthreads();
    if (t == 0) atomicAdd(&sum[l * 256 + n], wsum[0] + wsum[1] + wsum[2] + wsum[3]);
    __syncthreads();
  }
}

// ---------------- Gram: G_l += P_l P_l^T  (bf16 MFMA, lower quadrants) -------
__global__ __launch_bounds__(256) void k_gram(const unsigned short* __restrict__ P,
                                              const int* __restrict__ off,
                                              float* __restrict__ G) {
  int l = blockIdx.y;
  long o0 = off[l], o1 = off[l + 1];
  long k0 = o0 + (long)blockIdx.x * 1024;
  if (k0 >= o1) return;
  long rem = o1 - k0;
  int ks = rem > 1024 ? 1024 : (int)rem;     // always a multiple of 512
  int qi = (blockIdx.z == 0) ? 0 : 1;
  int qj = (blockIdx.z == 2) ? 1 : 0;

  __shared__ unsigned short As[128 * LDA];
  __shared__ unsigned short Bs[128 * LDA];

  int t = threadIdx.x;
  int wave = t >> 6, lane = t & 63;
  int wr = (wave >> 1) * 64, wc = (wave & 1) * 64;

  f32x4 acc[4][4] = {};

  for (int kk = 0; kk < ks; kk += 32) {
#pragma unroll
    for (int it = 0; it < 2; ++it) {
      int slot = t + it * 256;
      int rr = slot >> 2, gg = slot & 3;
      *(uint4*)&As[rr * LDA + gg * 8] =
          *(const uint4*)&P[(size_t)(qi * 128 + rr) * MPAD + (size_t)(k0 + kk) + gg * 8];
      *(uint4*)&Bs[rr * LDA + gg * 8] =
          *(const uint4*)&P[(size_t)(qj * 128 + rr) * MPAD + (size_t)(k0 + kk) + gg * 8];
    }
    __syncthreads();
    bf16x8 bfr[4];
#pragma unroll
    for (int fj = 0; fj < 4; ++fj)
      bfr[fj] = *(const bf16x8*)&Bs[(wc + fj * 16 + (lane & 15)) * LDA + (lane >> 4) * 8];
#pragma unroll
    for (int fi = 0; fi < 4; ++fi) {
      bf16x8 afr = *(const bf16x8*)&As[(wr + fi * 16 + (lane & 15)) * LDA + (lane >> 4) * 8];
#pragma unroll
      for (int fj = 0; fj < 4; ++fj)
        acc[fi][fj] = __builtin_amdgcn_mfma_f32_16x16x32_bf16(afr, bfr[fj], acc[fi][fj], 0, 0, 0);
    }
    __syncthreads();
  }
  float* Gl = G + ((size_t)l << 16);
  int rb = qi * 128 + wr, cb = qj * 128 + wc;
#pragma unroll
  for (int fi = 0; fi < 4; ++fi)
#pragma unroll
    for (int fj = 0; fj < 4; ++fj) {
      int cc = cb + fj * 16 + (lane & 15);
#pragma unroll
      for (int rg = 0; rg < 4; ++rg) {
        int rr = rb + fi * 16 + (lane >> 4) * 4 + rg;
        atomicAdd(&Gl[rr * 256 + cc], acc[fi][fj][rg]);
      }
    }
}

// ---------------- cov: read lower row-major, write TRANSPOSED in place -------
__global__ __launch_bounds__(256) void k_cov(float* __restrict__ G,
                                             const float* __restrict__ sum,
                                             const int* __restrict__ cnt,
                                             float* __restrict__ means) {
  int bid = blockIdx.x;                       // side*8 + l
  float* A = G + ((size_t)bid << 16);
  int t = threadIdx.x;
  __shared__ float mu[256];
  float fc = (float)cnt[bid];
  float m = sum[bid * 256 + t] / fmaxf(fc, 1.0f);
  mu[t] = m;
  means[bid * 256 + t] = m;
  __syncthreads();
  float rdiv = 1.0f / fmaxf(fmaxf(fc, 1.0f) - 1.0f, 1.0f);
  float mt = mu[t];
  for (int i = t; i < 256; ++i) {
    float g = A[i * 256 + t];
    A[t * 256 + i] = (g - fc * mu[i] * mt) * rdiv;
  }
}

// ---------------- panel step: factor 32x32 diag + W=L11^{-1} + L21 ----------
__global__ __launch_bounds__(256) void k_panel(float* __restrict__ G,
                                               float* __restrict__ Wg,
                                               int pb) {
  float* LT = G + ((size_t)blockIdx.x << 16);
  int t = threadIdx.x;
  int jbase = pb * 32;
  int H2 = 224 - jbase;
  __shared__ float Wl[32 * 36];

  if (t < 64) {
    int l32 = t & 31;
    float x[32];
#pragma unroll
    for (int k = 0; k < 32; ++k)
      x[k] = (k <= l32) ? LT[(size_t)(jbase + k) * 256 + jbase + l32] : 0.0f;
#pragma unroll
    for (int j = 0; j < 32; ++j) {
      float dj = __shfl(x[j], j, 64);
      float rd = 1.0f / sqrtf(dj);
      float lj = x[j] * rd;
      x[j] = lj;
#pragma unroll
      for (int k = j + 1; k < 32; ++k) {
        float lkj = __shfl(lj, k, 64);
        x[k] -= lj * lkj;
      }
    }
    if (t < 32) {
#pragma unroll
      for (int k = 0; k < 32; ++k)
        if (k <= l32) LT[(size_t)(jbase + k) * 256 + jbase + l32] = x[k];
    }
    float w[32];
#pragma unroll
    for (int k = 0; k < 32; ++k) w[k] = 0.0f;
#pragma unroll
    for (int i2 = 0; i2 < 32; ++i2) {
      float s = (i2 == l32) ? 1.0f : 0.0f;
#pragma unroll
      for (int k = 0; k < 32; ++k)
        if (k < i2) s -= __shfl(x[k], i2, 64) * w[k];
      float Lii = __shfl(x[i2], i2, 64);
      float wv = s / Lii;
      w[i2] = (i2 >= l32) ? wv : 0.0f;
    }
    if (t < 32) {
      float* Wgp = Wg + (((size_t)blockIdx.x * 8 + pb) << 10);
#pragma unroll
      for (int i2 = 0; i2 < 32; ++i2)
        if (i2 >= l32) {
          Wl[i2 * 36 + l32] = w[i2];
          Wgp[i2 * 32 + l32] = w[i2];
        }
    }
  }
  __syncthreads();

  if (t < H2) {
    int r = jbase + 32 + t;
    float a[32];
#pragma unroll
    for (int k = 0; k < 32; ++k) a[k] = LT[(size_t)(jbase + k) * 256 + r];
#pragma unroll
    for (int j = 0; j < 32; ++j) {
      float s = 0.0f;
#pragma unroll
      for (int k = 0; k < 32; ++k)
        if (k <= j) s += a[k] * Wl[j * 36 + k];
      LT[(size_t)(jbase + j) * 256 + r] = s;
    }
  }
}

// ---------------- trailing step: A22 -= L21 * L21^T (wide, 64x64 tiles) ------
__global__ __launch_bounds__(256) void k_trail(float* __restrict__ G, int pb) {
  int jbase = pb * 32;
  int H2 = 224 - jbase;
  int nts2 = (H2 + 63) >> 6;
  int y = blockIdx.y;
  if (y >= (nts2 * (nts2 + 1)) >> 1) return;
  int ti = 0;
  while ((((ti + 1) * (ti + 2)) >> 1) <= y) ++ti;
  int tj = y - ((ti * (ti + 1)) >> 1);
  float* LT = G + ((size_t)blockIdx.x << 16);
  int i0 = jbase + 32 + ti * 64;
  int j0 = jbase + 32 + tj * 64;

  __shared__ float Li[32][64];
  __shared__ float Lj[32][64];
  int t = threadIdx.x;
  for (int idx = t; idx < 2048; idx += 256) {
    int k = idx >> 6, r = idx & 63;
    Li[k][r] = (i0 + r < 256) ? LT[(size_t)(jbase + k) * 256 + i0 + r] : 0.0f;
    Lj[k][r] = (j0 + r < 256) ? LT[(size_t)(jbase + k) * 256 + j0 + r] : 0.0f;
  }
  __syncthreads();

  int tx = t & 15, ty = t >> 4;
  float acc[4][4] = {};
#pragma unroll
  for (int k = 0; k < 32; ++k) {
    float4 a = *(const float4*)&Li[k][ty * 4];
    float4 b = *(const float4*)&Lj[k][tx * 4];
    acc[0][0] += a.x * b.x; acc[0][1] += a.x * b.y; acc[0][2] += a.x * b.z; acc[0][3] += a.x * b.w;
    acc[1][0] += a.y * b.x; acc[1][1] += a.y * b.y; acc[1][2] += a.y * b.z; acc[1][3] += a.y * b.w;
    acc[2][0] += a.z * b.x; acc[2][1] += a.z * b.y; acc[2][2] += a.z * b.z; acc[2][3] += a.z * b.w;
    acc[3][0] += a.w * b.x; acc[3][1] += a.w * b.y; acc[3][2] += a.w * b.z; acc[3][3] += a.w * b.w;
  }
#pragma unroll
  for (int jj = 0; jj < 4; ++jj) {
    int j = j0 + tx * 4 + jj;
    if (j >= 256) continue;
    float* col = &LT[(size_t)j * 256 + i0 + ty * 4];
#pragma unroll
    for (int ii = 0; ii < 4; ++ii) {
      int i = i0 + ty * 4 + ii;
      if (i < 256 && i >= j) col[ii] -= acc[ii][jj];
    }
  }
}

// ---------------- T = Ls * Lc^{-1}: blocked right-looking solve --------------
#define RQ_INIT(q, rq)                                                          \
  _Pragma("unroll") for (int kl = 0; kl < 32; ++kl) {                           \
    int kg = h * 128 + q * 32 + kl;                                             \
    rq[kl] = (i >= kg) ? Ls[(size_t)kg * 256 + i] : 0.0f;                       \
  }

#define SOLVE_QW(rq)                                                            \
  _Pragma("unroll") for (int jl = 0; jl < 32; ++jl) {                           \
    float s = 0.0f;                                                             \
    _Pragma("unroll") for (int kl = 0; kl < 32; ++kl)                           \
      if (kl >= jl) s += rq[kl] * Wp[kl * 36 + jl];                             \
    Tp[i * 33 + jl] = s;                                                        \
  }

#define P2Q(q, rq)                                                              \
  if ((h * 128 + q * 32 + 32) <= jbase) {                                       \
    _Pragma("unroll") for (int kg = 0; kg < 8; ++kg) {                          \
      _Pragma("unroll") for (int jl = 0; jl < 32; ++jl) {                       \
        const float4 lc =                                                       \
            *(const float4*)&LcRows[jl * 260 + h * 128 + q * 32 + kg * 4];      \
        rq[kg * 4 + 0] -= tv[jl] * lc.x;                                        \
        rq[kg * 4 + 1] -= tv[jl] * lc.y;                                        \
        rq[kg * 4 + 2] -= tv[jl] * lc.z;                                        \
        rq[kg * 4 + 3] -= tv[jl] * lc.w;                                        \
      }                                                                         \
    }                                                                           \
  }

__global__ __launch_bounds__(512) void k_T(const float* __restrict__ G,
                                           const float* __restrict__ Wg,
                                           const float* __restrict__ means,
                                           const int* __restrict__ valid,
                                           unsigned short* __restrict__ Tb,
                                           float* __restrict__ bvec) {
  int l = blockIdx.x;
  int t = threadIdx.x;
  unsigned short* Tbl = Tb + ((size_t)l << 16);
  if (!valid[l]) {
    for (int x = t; x < 65536; x += 512) {
      int rr = x >> 8, cc = x & 255;
      Tbl[x] = f2bf(rr == cc ? 1.0f : 0.0f);
    }
    if (t < 256) bvec[l * 256 + t] = 0.0f;
    return;
  }
  const float* Lc = G + ((size_t)l << 16);        // content L, LT (col-major)
  const float* Ls = G + ((size_t)(8 + l) << 16);  // style L, LT (col-major)

  __shared__ float Tp[256 * 33];
  __shared__ float LcRows[32 * 260];
  __shared__ float Wp[32 * 36];
  __shared__ float muc[256];

  int i = t & 255, h = t >> 8;

  if (t < 256) muc[t] = means[l * 256 + t];

  float r0[32], r1[32], r2[32], r3[32];
  RQ_INIT(0, r0) RQ_INIT(1, r1) RQ_INIT(2, r2) RQ_INIT(3, r3)
  float bacc = 0.0f;

#pragma unroll 1
  for (int jb = 7; jb >= 0; --jb) {
    int jbase = jb * 32;
    __syncthreads();                              // protect LDS from prev readers
    for (int idx = t; idx < 32 * 256; idx += 512) {
      int c = idx >> 5, jl = idx & 31;
      int j = jbase + jl;
      LcRows[jl * 260 + c] = (c <= j) ? Lc[(size_t)c * 256 + j] : 0.0f;
    }
    for (int idx = t; idx < 1024; idx += 512)
      Wp[(idx >> 5) * 36 + (idx & 31)] = Wg[(((size_t)l * 8 + jb) << 10) + idx];
    __syncthreads();

    if (h == (jb >> 2)) {
      int q = jb & 3;
      if (q == 0) { SOLVE_QW(r0) }
      else if (q == 1) { SOLVE_QW(r1) }
      else if (q == 2) { SOLVE_QW(r2) }
      else { SOLVE_QW(r3) }
    }
    __syncthreads();

#pragma unroll
    for (int e = 0; e < 16; ++e) {
      int jl = h * 16 + e;
      Tbl[(size_t)i * 256 + jbase + jl] = f2bf(Tp[i * 33 + jl]);
    }
    if (h == 0) {
#pragma unroll
      for (int jl = 0; jl < 32; ++jl) bacc += Tp[i * 33 + jl] * muc[jbase + jl];
    }

    float tv[32];
#pragma unroll
    for (int jl = 0; jl < 32; ++jl) tv[jl] = Tp[i * 33 + jl];
    P2Q(0, r0) P2Q(1, r1) P2Q(2, r2) P2Q(3, r3)
  }

  if (h == 0) bvec[l * 256 + i] = means[(8 + l) * 256 + i] - bacc;
}

// ---------------- out = T_l * x + b_l on packed pixels (in place in P) -------
__global__ __launch_bounds__(256) void k_outgemm(unsigned short* __restrict__ P,
                                                 const unsigned short* __restrict__ Tb,
                                                 const float* __restrict__ bvec,
                                                 const int* __restrict__ off) {
  long px0 = (long)blockIdx.x * 128;
  if (px0 >= off[8]) return;
  int l = 0;
  while (l < 7 && px0 >= off[l + 1]) ++l;
  const unsigned short* Tl = Tb + ((size_t)l << 16);

  __shared__ unsigned short As[256 * LDA];
  __shared__ unsigned short Bs[128 * LDA];
  __shared__ float bsh[256];

  int t = threadIdx.x, wave = t >> 6, lane = t & 63;
  int wrow = wave * 64;
  bsh[t] = bvec[l * 256 + t];

  f32x4 acc[4][8] = {};

  for (int kk = 0; kk < 256; kk += 32) {
#pragma unroll
    for (int it = 0; it < 4; ++it) {            // A: 256 rows x 32 k
      int slot = t + it * 256;
      int rr = slot >> 2, gg = slot & 3;
      *(uint4*)&As[rr * LDA + gg * 8] = *(const uint4*)&Tl[rr * 256 + kk + gg * 8];
    }
#pragma unroll
    for (int it = 0; it < 2; ++it) {            // B: transpose-stage 32k x 128px
      int slot = t + it * 256;
      int pg = slot & 15, kr = slot >> 4;
      uint4 v = *(const uint4*)&P[(size_t)(kk + kr) * MPAD + px0 + pg * 8];
      const unsigned short* vs = (const unsigned short*)&v;
      int krs = kr ^ ((pg & 3) << 3);           // k-block XOR swizzle (bank spread)
#pragma unroll
      for (int e = 0; e < 8; ++e) Bs[(pg * 8 + e) * LDA + krs] = vs[e];
    }
    __syncthreads();
    if (kk < wrow + 64) {                       // T is lower-triangular: skip dead k-tiles
      bf16x8 bfr[8];
#pragma unroll
      for (int fj = 0; fj < 8; ++fj) {
        int px = fj * 16 + (lane & 15);
        int gs = (lane >> 4) ^ ((px >> 3) & 3);
        bfr[fj] = *(const bf16x8*)&Bs[px * LDA + gs * 8];
      }
#pragma unroll
      for (int fi = 0; fi < 4; ++fi) {
        if (wrow + fi * 16 + 15 >= kk) {
          bf16x8 afr = *(const bf16x8*)&As[(wrow + fi * 16 + (lane & 15)) * LDA + (lane >> 4) * 8];
#pragma unroll
          for (int fj = 0; fj < 8; ++fj)
            acc[fi][fj] = __builtin_amdgcn_mfma_f32_16x16x32_bf16(afr, bfr[fj], acc[fi][fj], 0, 0, 0);
        }
      }
    }
    __syncthreads();
  }
#pragma unroll
  for (int fi = 0; fi < 4; ++fi)
#pragma unroll
    for (int fj = 0; fj < 8; ++fj) {
      long p = px0 + fj * 16 + (lane & 15);
#pragma unroll
      for (int rg = 0; rg < 4; ++rg) {
        int rr = wrow + fi * 16 + (lane >> 4) * 4 + rg;
        float v = acc[fi][fj][rg] + bsh[rr];
        P[(size_t)rr * MPAD + p] = f2bf(v);
      }
    }
}

// =============================================================================
extern "C" void kernel_launch(void* const* d_in, const int* in_sizes, int n_in,
                              void* d_out, int out_size, void* d_ws, size_t ws_size,
                              hipStream_t stream) {
  const float* cfeat = (const float*)d_in[0];
  const float* sfeat = (const float*)d_in[1];
  const int* seg_c   = (const int*)d_in[2];
  const int* seg_s   = (const int*)d_in[3];

  char* ws = (char*)d_ws;
  size_t o = 0;
  auto take = [&](size_t b) { size_t r = o; o += (b + 255) & ~(size_t)255; return r; };

  unsigned short* P  = (unsigned short*)(ws + take((size_t)NCH * MPAD * 2));
  size_t zero_b = o;
  float* G           = (float*)(ws + take((size_t)2 * 8 * 65536 * 4));
  float* sum         = (float*)(ws + take((size_t)2 * 8 * 256 * 4));
  int*   hist        = (int*)(ws + take((size_t)2 * 128 * 8 * 4));
  size_t zero_e = o;
  unsigned short* Tb = (unsigned short*)(ws + take((size_t)8 * 65536 * 2));
  float* Wg          = (float*)(ws + take((size_t)16 * 8 * 1024 * 4));
  int*   dst         = (int*)(ws + take((size_t)2 * M_PIX * 4));
  float* means       = (float*)(ws + take((size_t)2 * 8 * 256 * 4));
  float* bvec        = (float*)(ws + take((size_t)8 * 256 * 4));
  int*   base        = (int*)(ws + take((size_t)2 * 128 * 8 * 4));
  int*   off         = (int*)(ws + take((size_t)2 * 9 * 4));
  int*   cnt         = (int*)(ws + take((size_t)2 * 8 * 4));
  int*   valid       = (int*)(ws + take((size_t)8 * 4));
  (void)ws_size; (void)n_in; (void)in_sizes; (void)out_size;

  hipMemsetAsync(ws + zero_b, 0, zero_e - zero_b, stream);

  k_hist<<<dim3(128), dim3(256), 0, stream>>>(seg_c, seg_s, hist);
  k_scan<<<dim3(1), dim3(256), 0, stream>>>(hist, base, off, cnt, valid);
  k_rank<<<dim3(128), dim3(256), 0, stream>>>(seg_c, seg_s, base, dst);

  // style (side 1) first, then content (side 0); P is reused, stream-serial.
  for (int s = 1; s >= 0; --s) {
    const float* feat = s ? sfeat : cfeat;
    const int* seg = s ? seg_s : seg_c;
    k_padzero<<<dim3(9), dim3(256), 0, stream>>>(P, off + s * 9, cnt + s * 8);
    k_pack<<<dim3(128, 8), dim3(256), 0, stream>>>(feat, seg, dst + (size_t)s * M_PIX,
                                                   base + s * 1024, P);
    k_psum<<<dim3(520, 32), dim3(256), 0, stream>>>(P, off + s * 9, sum + (size_t)s * 8 * 256);
    k_gram<<<dim3(260, 8, 3), dim3(256), 0, stream>>>(P, off + s * 9, G + (size_t)s * 8 * 65536);
  }

  k_cov<<<dim3(16), dim3(256), 0, stream>>>(G, sum, cnt, means);
  for (int pb = 0; pb < 8; ++pb) {
    k_panel<<<dim3(16), dim3(256), 0, stream>>>(G, Wg, pb);
    if (pb < 7) k_trail<<<dim3(16, 10), dim3(256), 0, stream>>>(G, pb);
  }
  k_T<<<dim3(8), dim3(512), 0, stream>>>(G, Wg, means, valid, Tb, bvec);
  k_outgemm<<<dim3(2080), dim3(256), 0, stream>>>(P, Tb, bvec, off);
  k_unpack<<<dim3(128, 8), dim3(256), 0, stream>>>(P, seg_c, dst, base, (float*)d_out);
}

// Round 8
// 1156.421 us; speedup vs baseline: 1.8217x; 1.1310x over previous
//
#include <hip/hip_runtime.h>

#define NCH   256
#define M_PIX 262144
#define MPAD  266240   // 520*512 ; >= M_PIX + 8*512 worst-case alignment pad
#define LDA   40       // padded LDS leading dim (bf16 elements) for 32-wide k tiles

typedef short bf16x8 __attribute__((ext_vector_type(8)));
typedef float f32x4  __attribute__((ext_vector_type(4)));

__device__ __forceinline__ unsigned short f2bf(float f) {
  union { float f; unsigned u; } v; v.f = f;
  unsigned r = v.u + 0x7FFFu + ((v.u >> 16) & 1u);
  return (unsigned short)(r >> 16);
}
__device__ __forceinline__ float bf2f(unsigned short h) {
  union { unsigned u; float f; } v; v.u = ((unsigned)h) << 16;
  return v.f;
}

// ---------------- histogram: per-2048-pixel-block label counts, both segs ----
__global__ __launch_bounds__(256) void k_hist(const int* __restrict__ seg_c,
                                              const int* __restrict__ seg_s,
                                              int* __restrict__ hist) {
  __shared__ int h[16];
  int t = threadIdx.x;
  if (t < 16) h[t] = 0;
  __syncthreads();
  int p0 = blockIdx.x * 2048 + t * 8;
#pragma unroll
  for (int e = 0; e < 8; ++e) {
    atomicAdd(&h[seg_c[p0 + e] & 7], 1);
    atomicAdd(&h[8 + (seg_s[p0 + e] & 7)], 1);
  }
  __syncthreads();
  if (t < 8) hist[blockIdx.x * 8 + t] = h[t];
  else if (t < 16) hist[1024 + blockIdx.x * 8 + (t - 8)] = h[t];
}

// ---------------- scan: totals, 512-aligned offsets, per-block bases, valid --
__global__ __launch_bounds__(256) void k_scan(const int* __restrict__ hist,
                                              int* __restrict__ base,
                                              int* __restrict__ off,
                                              int* __restrict__ cnt,
                                              int* __restrict__ valid) {
  __shared__ int lh[2048];
  __shared__ int tot[16];
  __shared__ int loff[2][9];
  int t = threadIdx.x;
  for (int i = t; i < 2048; i += 256) lh[i] = hist[i];
  __syncthreads();
  if (t < 16) {
    int s = t >> 3, l = t & 7, acc = 0;
    for (int b = 0; b < 128; ++b) acc += lh[s * 1024 + b * 8 + l];
    tot[t] = acc;
  }
  __syncthreads();
  if (t < 2) {
    int run = 0;
    for (int l = 0; l < 8; ++l) {
      loff[t][l] = run;
      run = (run + tot[t * 8 + l] + 511) & ~511;
    }
    loff[t][8] = run;
    for (int l = 0; l < 9; ++l) off[t * 9 + l] = loff[t][l];
    for (int l = 0; l < 8; ++l) cnt[t * 8 + l] = tot[t * 8 + l];
  }
  __syncthreads();
  if (t < 8) {
    long nc = tot[t], ns = tot[8 + t];
    valid[t] = (nc > 10 && ns > 10 && nc < 100 * ns && ns < 100 * nc) ? 1 : 0;
  }
  if (t < 16) {
    int s = t >> 3, l = t & 7;
    int run = loff[s][l];
    for (int b = 0; b < 128; ++b) {
      base[s * 1024 + b * 8 + l] = run;
      run += lh[s * 1024 + b * 8 + l];
    }
  }
}

// ---------------- rank: stable per-pixel destination slot (counting sort) ----
__global__ __launch_bounds__(256) void k_rank(const int* __restrict__ seg_c,
                                              const int* __restrict__ seg_s,
                                              const int* __restrict__ base,
                                              int* __restrict__ dst) {
  __shared__ int sc[8 * 272];
  __shared__ int rb[256 * 8];
  __shared__ int bb[8];
  int t = threadIdx.x;
  for (int s = 0; s < 2; ++s) {
    const int* seg = s ? seg_s : seg_c;
    const int* bas = base + s * 1024 + blockIdx.x * 8;
    int* dd = dst + (size_t)s * M_PIX;
    int p0 = blockIdx.x * 2048 + t * 8;
    unsigned pk2 = 0, cpk = 0;
#pragma unroll
    for (int e = 0; e < 8; ++e) {
      int lb = seg[p0 + e] & 7;
      pk2 |= (unsigned)lb << (3 * e);
      cpk += 1u << (4 * lb);
    }
#pragma unroll
    for (int lq = 0; lq < 8; ++lq) sc[lq * 272 + t] = (int)((cpk >> (4 * lq)) & 15u);
    if (t < 8) bb[t] = bas[t];
    __syncthreads();
    for (int d = 1; d < 256; d <<= 1) {
      int v[8];
#pragma unroll
      for (int lq = 0; lq < 8; ++lq)
        v[lq] = sc[lq * 272 + t] + ((t >= d) ? sc[lq * 272 + t - d] : 0);
      __syncthreads();
#pragma unroll
      for (int lq = 0; lq < 8; ++lq) sc[lq * 272 + t] = v[lq];
      __syncthreads();
    }
#pragma unroll
    for (int lq = 0; lq < 8; ++lq)
      rb[t * 8 + lq] = bb[lq] + sc[lq * 272 + t] - (int)((cpk >> (4 * lq)) & 15u);
#pragma unroll
    for (int e = 0; e < 8; ++e) {
      int lb = (int)((pk2 >> (3 * e)) & 7u);
      int dpos = rb[t * 8 + lb]++;
      dd[p0 + e] = dpos;
    }
    __syncthreads();
  }
}

// ---------------- zero the alignment pads of P -------------------------------
__global__ __launch_bounds__(256) void k_padzero(unsigned short* __restrict__ P,
                                                 const int* __restrict__ off,
                                                 const int* __restrict__ cnt) {
  int l = blockIdx.x;
  int c0, c1;
  if (l < 8) { c0 = off[l] + cnt[l]; c1 = off[l + 1]; }
  else       { c0 = off[8];          c1 = MPAD; }
  int w = c1 - c0;
  if (w <= 0) return;
  for (int r = 0; r < 256; ++r)
    for (int cc = threadIdx.x; cc < w; cc += 256)
      P[(size_t)r * MPAD + c0 + cc] = 0;
}

// ---------------- pack: coalesced-both-sides via LDS local sort --------------
__global__ __launch_bounds__(256) void k_pack(const float* __restrict__ feat,
                                              const int* __restrict__ seg,
                                              const int* __restrict__ dst,
                                              const int* __restrict__ base,
                                              unsigned short* __restrict__ P) {
  int b = blockIdx.x, g = blockIdx.y, t = threadIdx.x;
  int p0 = b * 2048;
  __shared__ unsigned short buf[8][2048];
  __shared__ int h[8], lbase[9], gbase[8];
  if (t < 8) { h[t] = 0; gbase[t] = base[b * 8 + t]; }
  __syncthreads();
  int lb[8], slot[8], gd[8];
#pragma unroll
  for (int i = 0; i < 8; ++i) {
    lb[i] = seg[p0 + i * 256 + t] & 7;
    atomicAdd(&h[lb[i]], 1);
  }
  __syncthreads();
  if (t == 0) {
    int run = 0;
    for (int l = 0; l < 8; ++l) { lbase[l] = run; run += h[l]; }
    lbase[8] = run;
  }
  __syncthreads();
#pragma unroll
  for (int i = 0; i < 8; ++i)
    slot[i] = lbase[lb[i]] + (dst[p0 + i * 256 + t] - gbase[lb[i]]);
#pragma unroll
  for (int i = 0; i < 8; ++i) {
    int q = i * 256 + t;
    int l = 0;
    while (l < 7 && q >= lbase[l + 1]) ++l;
    gd[i] = gbase[l] + q - lbase[l];
  }
  int n0 = g * 32;
#pragma unroll 1
  for (int cp = 0; cp < 4; ++cp) {
#pragma unroll
    for (int c = 0; c < 8; ++c) {
      const float* fp = &feat[(size_t)(n0 + cp * 8 + c) * M_PIX + p0];
#pragma unroll
      for (int i = 0; i < 8; ++i)
        buf[c][slot[i]] = f2bf(fp[i * 256 + t]);
    }
    __syncthreads();
#pragma unroll
    for (int c = 0; c < 8; ++c) {
      unsigned short* pp = &P[(size_t)(n0 + cp * 8 + c) * MPAD];
#pragma unroll
      for (int i = 0; i < 8; ++i)
        pp[gd[i]] = buf[c][i * 256 + t];
    }
    __syncthreads();
  }
}

// ---------------- unpack: mirrored (contiguous reads, coalesced f32 writes) --
__global__ __launch_bounds__(256) void k_unpack(const unsigned short* __restrict__ P,
                                                const int* __restrict__ seg,
                                                const int* __restrict__ dst,
                                                const int* __restrict__ base,
                                                float* __restrict__ out) {
  int b = blockIdx.x, g = blockIdx.y, t = threadIdx.x;
  int p0 = b * 2048;
  __shared__ unsigned short buf[8][2048];
  __shared__ int h[8], lbase[9], gbase[8];
  if (t < 8) { h[t] = 0; gbase[t] = base[b * 8 + t]; }
  __syncthreads();
  int lb[8], slot[8], gd[8];
#pragma unroll
  for (int i = 0; i < 8; ++i) {
    lb[i] = seg[p0 + i * 256 + t] & 7;
    atomicAdd(&h[lb[i]], 1);
  }
  __syncthreads();
  if (t == 0) {
    int run = 0;
    for (int l = 0; l < 8; ++l) { lbase[l] = run; run += h[l]; }
    lbase[8] = run;
  }
  __syncthreads();
#pragma unroll
  for (int i = 0; i < 8; ++i)
    slot[i] = lbase[lb[i]] + (dst[p0 + i * 256 + t] - gbase[lb[i]]);
#pragma unroll
  for (int i = 0; i < 8; ++i) {
    int q = i * 256 + t;
    int l = 0;
    while (l < 7 && q >= lbase[l + 1]) ++l;
    gd[i] = gbase[l] + q - lbase[l];
  }
  int n0 = g * 32;
#pragma unroll 1
  for (int cp = 0; cp < 4; ++cp) {
#pragma unroll
    for (int c = 0; c < 8; ++c) {
      const unsigned short* pp = &P[(size_t)(n0 + cp * 8 + c) * MPAD];
#pragma unroll
      for (int i = 0; i < 8; ++i)
        buf[c][i * 256 + t] = pp[gd[i]];
    }
    __syncthreads();
#pragma unroll
    for (int c = 0; c < 8; ++c) {
      float* op = &out[(size_t)(n0 + cp * 8 + c) * M_PIX + p0];
#pragma unroll
      for (int i = 0; i < 8; ++i)
        op[i * 256 + t] = bf2f(buf[c][slot[i]]);
    }
    __syncthreads();
  }
}

// ---------------- Gram (unified) + fused row sums ---------------------------
// One 512-thread block per (1024-px chunk, label): stage ALL 256 rows x 32k
// once (vs 3 quadrant-blocks re-staging halves: 3x less HBM read). Waves 0-5
// compute the 3 lower 128x128 quadrants as 64x128 strips. Threads 0-255 also
// accumulate per-row sums from the staged tile (replaces k_psum entirely).
__global__ __launch_bounds__(512) void k_gram(const unsigned short* __restrict__ P,
                                              const int* __restrict__ off,
                                              float* __restrict__ G,
                                              float* __restrict__ sum) {
  int l = blockIdx.y;
  long o0 = off[l], o1 = off[l + 1];
  long k0 = o0 + (long)blockIdx.x * 1024;
  if (k0 >= o1) return;
  long rem = o1 - k0;
  int ks = rem > 1024 ? 1024 : (int)rem;     // always a multiple of 512

  __shared__ unsigned short Sb[256 * LDA];
  int t = threadIdx.x, wave = t >> 6, lane = t & 63;
  int wr = (wave < 2) ? wave * 64 : 128 + (wave & 1) * 64;
  int wc = (wave >= 4) ? 128 : 0;
  bool wact = (wave < 6);

  f32x4 acc[4][8] = {};
  float rsum = 0.0f;

  for (int kk = 0; kk < ks; kk += 32) {
#pragma unroll
    for (int it = 0; it < 2; ++it) {
      int slot = t + it * 512;
      int rr = slot >> 2, gg = slot & 3;
      *(uint4*)&Sb[rr * LDA + gg * 8] =
          *(const uint4*)&P[(size_t)rr * MPAD + (size_t)(k0 + kk) + gg * 8];
    }
    __syncthreads();
    if (t < 256) {                            // fused psum: row t's 32 values
#pragma unroll
      for (int e = 0; e < 16; ++e) {
        unsigned v = *(const unsigned*)&Sb[t * LDA + e * 2];
        rsum += bf2f((unsigned short)(v & 0xFFFFu)) + bf2f((unsigned short)(v >> 16));
      }
    }
    if (wact) {
      bf16x8 bfr[8];
#pragma unroll
      for (int fj = 0; fj < 8; ++fj)
        bfr[fj] = *(const bf16x8*)&Sb[(wc + fj * 16 + (lane & 15)) * LDA + (lane >> 4) * 8];
#pragma unroll
      for (int fi = 0; fi < 4; ++fi) {
        bf16x8 afr = *(const bf16x8*)&Sb[(wr + fi * 16 + (lane & 15)) * LDA + (lane >> 4) * 8];
#pragma unroll
        for (int fj = 0; fj < 8; ++fj)
          acc[fi][fj] = __builtin_amdgcn_mfma_f32_16x16x32_bf16(afr, bfr[fj], acc[fi][fj], 0, 0, 0);
      }
    }
    __syncthreads();
  }
  float* Gl = G + ((size_t)l << 16);
  if (wact) {
#pragma unroll
    for (int fi = 0; fi < 4; ++fi)
#pragma unroll
      for (int fj = 0; fj < 8; ++fj) {
        int cc = wc + fj * 16 + (lane & 15);
#pragma unroll
        for (int rg = 0; rg < 4; ++rg) {
          int rr2 = wr + fi * 16 + (lane >> 4) * 4 + rg;
          atomicAdd(&Gl[rr2 * 256 + cc], acc[fi][fj][rg]);
        }
      }
  }
  if (t < 256) atomicAdd(&sum[l * 256 + t], rsum);
}

// ---------------- cov: read lower row-major, write TRANSPOSED in place -------
__global__ __launch_bounds__(256) void k_cov(float* __restrict__ G,
                                             const float* __restrict__ sum,
                                             const int* __restrict__ cnt,
                                             float* __restrict__ means) {
  int bid = blockIdx.x;                       // side*8 + l
  float* A = G + ((size_t)bid << 16);
  int t = threadIdx.x;
  __shared__ float mu[256];
  float fc = (float)cnt[bid];
  float m = sum[bid * 256 + t] / fmaxf(fc, 1.0f);
  mu[t] = m;
  means[bid * 256 + t] = m;
  __syncthreads();
  float rdiv = 1.0f / fmaxf(fmaxf(fc, 1.0f) - 1.0f, 1.0f);
  float mt = mu[t];
  for (int i = t; i < 256; ++i) {
    float g = A[i * 256 + t];
    A[t * 256 + i] = (g - fc * mu[i] * mt) * rdiv;
  }
}

// ---------------- panel step: factor 32x32 diag + W=L11^{-1} + L21 ----------
__global__ __launch_bounds__(256) void k_panel(float* __restrict__ G,
                                               float* __restrict__ Wg,
                                               int pb) {
  float* LT = G + ((size_t)blockIdx.x << 16);
  int t = threadIdx.x;
  int jbase = pb * 32;
  int H2 = 224 - jbase;
  __shared__ float Wl[32 * 36];

  if (t < 64) {
    int l32 = t & 31;
    float x[32];
#pragma unroll
    for (int k = 0; k < 32; ++k)
      x[k] = (k <= l32) ? LT[(size_t)(jbase + k) * 256 + jbase + l32] : 0.0f;
#pragma unroll
    for (int j = 0; j < 32; ++j) {
      float dj = __shfl(x[j], j, 64);
      float rd = 1.0f / sqrtf(dj);
      float lj = x[j] * rd;
      x[j] = lj;
#pragma unroll
      for (int k = j + 1; k < 32; ++k) {
        float lkj = __shfl(lj, k, 64);
        x[k] -= lj * lkj;
      }
    }
    if (t < 32) {
#pragma unroll
      for (int k = 0; k < 32; ++k)
        if (k <= l32) LT[(size_t)(jbase + k) * 256 + jbase + l32] = x[k];
    }
    float w[32];
#pragma unroll
    for (int k = 0; k < 32; ++k) w[k] = 0.0f;
#pragma unroll
    for (int i2 = 0; i2 < 32; ++i2) {
      float s = (i2 == l32) ? 1.0f : 0.0f;
#pragma unroll
      for (int k = 0; k < 32; ++k)
        if (k < i2) s -= __shfl(x[k], i2, 64) * w[k];
      float Lii = __shfl(x[i2], i2, 64);
      float wv = s / Lii;
      w[i2] = (i2 >= l32) ? wv : 0.0f;
    }
    if (t < 32) {
      float* Wgp = Wg + (((size_t)blockIdx.x * 8 + pb) << 10);
#pragma unroll
      for (int i2 = 0; i2 < 32; ++i2)
        if (i2 >= l32) {
          Wl[i2 * 36 + l32] = w[i2];
          Wgp[i2 * 32 + l32] = w[i2];
        }
    }
  }
  __syncthreads();

  if (t < H2) {
    int r = jbase + 32 + t;
    float a[32];
#pragma unroll
    for (int k = 0; k < 32; ++k) a[k] = LT[(size_t)(jbase + k) * 256 + r];
#pragma unroll
    for (int j = 0; j < 32; ++j) {
      float s = 0.0f;
#pragma unroll
      for (int k = 0; k < 32; ++k)
        if (k <= j) s += a[k] * Wl[j * 36 + k];
      LT[(size_t)(jbase + j) * 256 + r] = s;
    }
  }
}

// ---------------- trailing step: A22 -= L21 * L21^T (wide, 64x64 tiles) ------
__global__ __launch_bounds__(256) void k_trail(float* __restrict__ G, int pb) {
  int jbase = pb * 32;
  int H2 = 224 - jbase;
  int nts2 = (H2 + 63) >> 6;
  int y = blockIdx.y;
  if (y >= (nts2 * (nts2 + 1)) >> 1) return;
  int ti = 0;
  while ((((ti + 1) * (ti + 2)) >> 1) <= y) ++ti;
  int tj = y - ((ti * (ti + 1)) >> 1);
  float* LT = G + ((size_t)blockIdx.x << 16);
  int i0 = jbase + 32 + ti * 64;
  int j0 = jbase + 32 + tj * 64;

  __shared__ float Li[32][64];
  __shared__ float Lj[32][64];
  int t = threadIdx.x;
  for (int idx = t; idx < 2048; idx += 256) {
    int k = idx >> 6, r = idx & 63;
    Li[k][r] = (i0 + r < 256) ? LT[(size_t)(jbase + k) * 256 + i0 + r] : 0.0f;
    Lj[k][r] = (j0 + r < 256) ? LT[(size_t)(jbase + k) * 256 + j0 + r] : 0.0f;
  }
  __syncthreads();

  int tx = t & 15, ty = t >> 4;
  float acc[4][4] = {};
#pragma unroll
  for (int k = 0; k < 32; ++k) {
    float4 a = *(const float4*)&Li[k][ty * 4];
    float4 b = *(const float4*)&Lj[k][tx * 4];
    acc[0][0] += a.x * b.x; acc[0][1] += a.x * b.y; acc[0][2] += a.x * b.z; acc[0][3] += a.x * b.w;
    acc[1][0] += a.y * b.x; acc[1][1] += a.y * b.y; acc[1][2] += a.y * b.z; acc[1][3] += a.y * b.w;
    acc[2][0] += a.z * b.x; acc[2][1] += a.z * b.y; acc[2][2] += a.z * b.z; acc[2][3] += a.z * b.w;
    acc[3][0] += a.w * b.x; acc[3][1] += a.w * b.y; acc[3][2] += a.w * b.z; acc[3][3] += a.w * b.w;
  }
#pragma unroll
  for (int jj = 0; jj < 4; ++jj) {
    int j = j0 + tx * 4 + jj;
    if (j >= 256) continue;
    float* col = &LT[(size_t)j * 256 + i0 + ty * 4];
#pragma unroll
    for (int ii = 0; ii < 4; ++ii) {
      int i = i0 + ty * 4 + ii;
      if (i < 256 && i >= j) col[ii] -= acc[ii][jj];
    }
  }
}

// ---------------- T = Ls * Lc^{-1}: blocked right-looking solve --------------
#define RQ_INIT(q, rq)                                                          \
  _Pragma("unroll") for (int kl = 0; kl < 32; ++kl) {                           \
    int kg = h * 128 + q * 32 + kl;                                             \
    rq[kl] = (i >= kg) ? Ls[(size_t)kg * 256 + i] : 0.0f;                       \
  }

#define SOLVE_QW(rq)                                                            \
  _Pragma("unroll") for (int jl = 0; jl < 32; ++jl) {                           \
    float s = 0.0f;                                                             \
    _Pragma("unroll") for (int kl = 0; kl < 32; ++kl)                           \
      if (kl >= jl) s += rq[kl] * Wp[kl * 36 + jl];                             \
    Tp[i * 33 + jl] = s;                                                        \
  }

#define P2Q(q, rq)                                                              \
  if ((h * 128 + q * 32 + 32) <= jbase) {                                       \
    _Pragma("unroll") for (int kg = 0; kg < 8; ++kg) {                          \
      _Pragma("unroll") for (int jl = 0; jl < 32; ++jl) {                       \
        const float4 lc =                                                       \
            *(const float4*)&LcRows[jl * 260 + h * 128 + q * 32 + kg * 4];      \
        rq[kg * 4 + 0] -= tv[jl] * lc.x;                                        \
        rq[kg * 4 + 1] -= tv[jl] * lc.y;                                        \
        rq[kg * 4 + 2] -= tv[jl] * lc.z;                                        \
        rq[kg * 4 + 3] -= tv[jl] * lc.w;                                        \
      }                                                                         \
    }                                                                           \
  }

__global__ __launch_bounds__(512) void k_T(const float* __restrict__ G,
                                           const float* __restrict__ Wg,
                                           const float* __restrict__ means,
                                           const int* __restrict__ valid,
                                           unsigned short* __restrict__ Tb,
                                           float* __restrict__ bvec) {
  int l = blockIdx.x;
  int t = threadIdx.x;
  unsigned short* Tbl = Tb + ((size_t)l << 16);
  if (!valid[l]) {
    for (int x = t; x < 65536; x += 512) {
      int rr = x >> 8, cc = x & 255;
      Tbl[x] = f2bf(rr == cc ? 1.0f : 0.0f);
    }
    if (t < 256) bvec[l * 256 + t] = 0.0f;
    return;
  }
  const float* Lc = G + ((size_t)l << 16);        // content L, LT (col-major)
  const float* Ls = G + ((size_t)(8 + l) << 16);  // style L, LT (col-major)

  __shared__ float Tp[256 * 33];
  __shared__ float LcRows[32 * 260];
  __shared__ float Wp[32 * 36];
  __shared__ float muc[256];

  int i = t & 255, h = t >> 8;

  if (t < 256) muc[t] = means[l * 256 + t];

  float r0[32], r1[32], r2[32], r3[32];
  RQ_INIT(0, r0) RQ_INIT(1, r1) RQ_INIT(2, r2) RQ_INIT(3, r3)
  float bacc = 0.0f;

#pragma unroll 1
  for (int jb = 7; jb >= 0; --jb) {
    int jbase = jb * 32;
    __syncthreads();                              // protect LDS from prev readers
    for (int idx = t; idx < 32 * 256; idx += 512) {
      int c = idx >> 5, jl = idx & 31;
      int j = jbase + jl;
      LcRows[jl * 260 + c] = (c <= j) ? Lc[(size_t)c * 256 + j] : 0.0f;
    }
    for (int idx = t; idx < 1024; idx += 512)
      Wp[(idx >> 5) * 36 + (idx & 31)] = Wg[(((size_t)l * 8 + jb) << 10) + idx];
    __syncthreads();

    if (h == (jb >> 2)) {
      int q = jb & 3;
      if (q == 0) { SOLVE_QW(r0) }
      else if (q == 1) { SOLVE_QW(r1) }
      else if (q == 2) { SOLVE_QW(r2) }
      else { SOLVE_QW(r3) }
    }
    __syncthreads();

#pragma unroll
    for (int e = 0; e < 16; ++e) {
      int jl = h * 16 + e;
      Tbl[(size_t)i * 256 + jbase + jl] = f2bf(Tp[i * 33 + jl]);
    }
    if (h == 0) {
#pragma unroll
      for (int jl = 0; jl < 32; ++jl) bacc += Tp[i * 33 + jl] * muc[jbase + jl];
    }

    float tv[32];
#pragma unroll
    for (int jl = 0; jl < 32; ++jl) tv[jl] = Tp[i * 33 + jl];
    P2Q(0, r0) P2Q(1, r1) P2Q(2, r2) P2Q(3, r3)
  }

  if (h == 0) bvec[l * 256 + i] = means[(8 + l) * 256 + i] - bacc;
}

// ---------------- out = T_l * x + b_l on packed pixels (in place in P) -------
__global__ __launch_bounds__(256) void k_outgemm(unsigned short* __restrict__ P,
                                                 const unsigned short* __restrict__ Tb,
                                                 const float* __restrict__ bvec,
                                                 const int* __restrict__ off) {
  long px0 = (long)blockIdx.x * 128;
  if (px0 >= off[8]) return;
  int l = 0;
  while (l < 7 && px0 >= off[l + 1]) ++l;
  const unsigned short* Tl = Tb + ((size_t)l << 16);

  __shared__ unsigned short As[256 * LDA];
  __shared__ unsigned short Bs[128 * LDA];
  __shared__ float bsh[256];

  int t = threadIdx.x, wave = t >> 6, lane = t & 63;
  int wrow = wave * 64;
  bsh[t] = bvec[l * 256 + t];

  f32x4 acc[4][8] = {};

  for (int kk = 0; kk < 256; kk += 32) {
#pragma unroll
    for (int it = 0; it < 4; ++it) {            // A: 256 rows x 32 k
      int slot = t + it * 256;
      int rr = slot >> 2, gg = slot & 3;
      *(uint4*)&As[rr * LDA + gg * 8] = *(const uint4*)&Tl[rr * 256 + kk + gg * 8];
    }
#pragma unroll
    for (int it = 0; it < 2; ++it) {            // B: transpose-stage 32k x 128px
      int slot = t + it * 256;
      int pg = slot & 15, kr = slot >> 4;
      uint4 v = *(const uint4*)&P[(size_t)(kk + kr) * MPAD + px0 + pg * 8];
      const unsigned short* vs = (const unsigned short*)&v;
      int krs = kr ^ ((pg & 3) << 3);           // k-block XOR swizzle (bank spread)
#pragma unroll
      for (int e = 0; e < 8; ++e) Bs[(pg * 8 + e) * LDA + krs] = vs[e];
    }
    __syncthreads();
    if (kk < wrow + 64) {                       // T is lower-triangular: skip dead k-tiles
      bf16x8 bfr[8];
#pragma unroll
      for (int fj = 0; fj < 8; ++fj) {
        int px = fj * 16 + (lane & 15);
        int gs = (lane >> 4) ^ ((px >> 3) & 3);
        bfr[fj] = *(const bf16x8*)&Bs[px * LDA + gs * 8];
      }
#pragma unroll
      for (int fi = 0; fi < 4; ++fi) {
        if (wrow + fi * 16 + 15 >= kk) {
          bf16x8 afr = *(const bf16x8*)&As[(wrow + fi * 16 + (lane & 15)) * LDA + (lane >> 4) * 8];
#pragma unroll
          for (int fj = 0; fj < 8; ++fj)
            acc[fi][fj] = __builtin_amdgcn_mfma_f32_16x16x32_bf16(afr, bfr[fj], acc[fi][fj], 0, 0, 0);
        }
      }
    }
    __syncthreads();
  }
#pragma unroll
  for (int fi = 0; fi < 4; ++fi)
#pragma unroll
    for (int fj = 0; fj < 8; ++fj) {
      long p = px0 + fj * 16 + (lane & 15);
#pragma unroll
      for (int rg = 0; rg < 4; ++rg) {
        int rr = wrow + fi * 16 + (lane >> 4) * 4 + rg;
        float v = acc[fi][fj][rg] + bsh[rr];
        P[(size_t)rr * MPAD + p] = f2bf(v);
      }
    }
}

// =============================================================================
extern "C" void kernel_launch(void* const* d_in, const int* in_sizes, int n_in,
                              void* d_out, int out_size, void* d_ws, size_t ws_size,
                              hipStream_t stream) {
  const float* cfeat = (const float*)d_in[0];
  const float* sfeat = (const float*)d_in[1];
  const int* seg_c   = (const int*)d_in[2];
  const int* seg_s   = (const int*)d_in[3];

  char* ws = (char*)d_ws;
  size_t o = 0;
  auto take = [&](size_t b) { size_t r = o; o += (b + 255) & ~(size_t)255; return r; };

  unsigned short* P  = (unsigned short*)(ws + take((size_t)NCH * MPAD * 2));
  size_t zero_b = o;
  float* G           = (float*)(ws + take((size_t)2 * 8 * 65536 * 4));
  float* sum         = (float*)(ws + take((size_t)2 * 8 * 256 * 4));
  int*   hist        = (int*)(ws + take((size_t)2 * 128 * 8 * 4));
  size_t zero_e = o;
  unsigned short* Tb = (unsigned short*)(ws + take((size_t)8 * 65536 * 2));
  float* Wg          = (float*)(ws + take((size_t)16 * 8 * 1024 * 4));
  int*   dst         = (int*)(ws + take((size_t)2 * M_PIX * 4));
  float* means       = (float*)(ws + take((size_t)2 * 8 * 256 * 4));
  float* bvec        = (float*)(ws + take((size_t)8 * 256 * 4));
  int*   base        = (int*)(ws + take((size_t)2 * 128 * 8 * 4));
  int*   off         = (int*)(ws + take((size_t)2 * 9 * 4));
  int*   cnt         = (int*)(ws + take((size_t)2 * 8 * 4));
  int*   valid       = (int*)(ws + take((size_t)8 * 4));
  (void)ws_size; (void)n_in; (void)in_sizes; (void)out_size;

  hipMemsetAsync(ws + zero_b, 0, zero_e - zero_b, stream);

  k_hist<<<dim3(128), dim3(256), 0, stream>>>(seg_c, seg_s, hist);
  k_scan<<<dim3(1), dim3(256), 0, stream>>>(hist, base, off, cnt, valid);
  k_rank<<<dim3(128), dim3(256), 0, stream>>>(seg_c, seg_s, base, dst);

  // style (side 1) first, then content (side 0); P is reused, stream-serial.
  for (int s = 1; s >= 0; --s) {
    const float* feat = s ? sfeat : cfeat;
    const int* seg = s ? seg_s : seg_c;
    k_padzero<<<dim3(9), dim3(256), 0, stream>>>(P, off + s * 9, cnt + s * 8);
    k_pack<<<dim3(128, 8), dim3(256), 0, stream>>>(feat, seg, dst + (size_t)s * M_PIX,
                                                   base + s * 1024, P);
    k_gram<<<dim3(260, 8), dim3(512), 0, stream>>>(P, off + s * 9, G + (size_t)s * 8 * 65536,
                                                   sum + (size_t)s * 8 * 256);
  }

  k_cov<<<dim3(16), dim3(256), 0, stream>>>(G, sum, cnt, means);
  for (int pb = 0; pb < 8; ++pb) {
    k_panel<<<dim3(16), dim3(256), 0, stream>>>(G, Wg, pb);
    if (pb < 7) k_trail<<<dim3(16, 10), dim3(256), 0, stream>>>(G, pb);
  }
  k_T<<<dim3(8), dim3(512), 0, stream>>>(G, Wg, means, valid, Tb, bvec);
  k_outgemm<<<dim3(2080), dim3(256), 0, stream>>>(P, Tb, bvec, off);
  k_unpack<<<dim3(128, 8), dim3(256), 0, stream>>>(P, seg_c, dst, base, (float*)d_out);
}